// Round 1
// baseline (1249.270 us; speedup 1.0000x reference)
//
#include <hip/hip_runtime.h>
#include <hip/hip_bf16.h>
#include <stdint.h>

// ---------------- types / helpers ----------------
typedef __attribute__((ext_vector_type(8))) short bf16x8;
typedef __attribute__((ext_vector_type(4))) float f32x4;

__device__ __forceinline__ short f2bf(float f) {
  __hip_bfloat16 h = __float2bfloat16(f);
  union { __hip_bfloat16 h; short s; } u; u.h = h; return u.s;
}

__device__ __forceinline__ float wave_sum64(float v) {
  #pragma unroll
  for (int off = 1; off < 64; off <<= 1) v += __shfl_xor(v, off);
  return v;
}
__device__ __forceinline__ double wave_sum64d(double v) {
  #pragma unroll
  for (int off = 1; off < 64; off <<= 1) v += __shfl_xor(v, off);
  return v;
}

// ---------------- LN kernels ----------------
__global__ __launch_bounds__(256) void ln_f32(const float* __restrict__ x,
    const float* __restrict__ g, const float* __restrict__ b, float* __restrict__ out) {
  int t = blockIdx.x, tid = threadIdx.x;
  const float4 v = ((const float4*)(x + (size_t)t * 1024))[tid];
  float s = v.x + v.y + v.z + v.w;
  float s2 = v.x*v.x + v.y*v.y + v.z*v.z + v.w*v.w;
  s = wave_sum64(s); s2 = wave_sum64(s2);
  __shared__ float pa[4], pb[4];
  int wid = tid >> 6, lane = tid & 63;
  if (lane == 0) { pa[wid] = s; pb[wid] = s2; }
  __syncthreads();
  float S = pa[0]+pa[1]+pa[2]+pa[3], S2 = pb[0]+pb[1]+pb[2]+pb[3];
  float mu = S * (1.f/1024.f);
  float var = S2 * (1.f/1024.f) - mu*mu;
  float rs = rsqrtf(var + 1e-5f);
  const float4 gv = ((const float4*)g)[tid];
  const float4 bv = ((const float4*)b)[tid];
  float4 o;
  o.x = (v.x-mu)*rs*gv.x + bv.x; o.y = (v.y-mu)*rs*gv.y + bv.y;
  o.z = (v.z-mu)*rs*gv.z + bv.z; o.w = (v.w-mu)*rs*gv.w + bv.w;
  ((float4*)(out + (size_t)t * 1024))[tid] = o;
}

__global__ __launch_bounds__(256) void ln_bf16(const float* __restrict__ x,
    const float* __restrict__ g, const float* __restrict__ b, short* __restrict__ out) {
  int t = blockIdx.x, tid = threadIdx.x;
  const float4 v = ((const float4*)(x + (size_t)t * 1024))[tid];
  float s = v.x + v.y + v.z + v.w;
  float s2 = v.x*v.x + v.y*v.y + v.z*v.z + v.w*v.w;
  s = wave_sum64(s); s2 = wave_sum64(s2);
  __shared__ float pa[4], pb[4];
  int wid = tid >> 6, lane = tid & 63;
  if (lane == 0) { pa[wid] = s; pb[wid] = s2; }
  __syncthreads();
  float S = pa[0]+pa[1]+pa[2]+pa[3], S2 = pb[0]+pb[1]+pb[2]+pb[3];
  float mu = S * (1.f/1024.f);
  float var = S2 * (1.f/1024.f) - mu*mu;
  float rs = rsqrtf(var + 1e-5f);
  const float4 gv = ((const float4*)g)[tid];
  const float4 bv = ((const float4*)b)[tid];
  short4 o;
  o.x = f2bf((v.x-mu)*rs*gv.x + bv.x); o.y = f2bf((v.y-mu)*rs*gv.y + bv.y);
  o.z = f2bf((v.z-mu)*rs*gv.z + bv.z); o.w = f2bf((v.w-mu)*rs*gv.w + bv.w);
  ((short4*)(out + (size_t)t * 1024))[tid] = o;
}

// ---------------- fp32 GEMM (precision-critical path) ----------------
// C[M x N] = A[M x 1024] @ B[1024 x N] (+bias)(+resid). 128x128 tile, 8x8 microtile.
// MODE 0: fused QKV  (grid.y: 0..7 -> Q (scaled 1/8), 8 -> K, 9 -> V)
// MODE 1: Wo + bias + residual -> fp32 out (h)
template<int MODE>
__global__ __launch_bounds__(256) void gemm_f32(
    const float* __restrict__ A,
    const float* __restrict__ W0, const float* __restrict__ W1, const float* __restrict__ W2,
    const float* __restrict__ b0, const float* __restrict__ b1, const float* __restrict__ b2,
    const float* __restrict__ resid,
    float* __restrict__ out0, float* __restrict__ out1, float* __restrict__ out2) {
  int m0 = blockIdx.x * 128;
  int y = blockIdx.y;
  const float* Bp; const float* bias; float* out; int ldb, n0, ldout; float scale = 1.f;
  if (MODE == 0) {
    if (y < 8)      { Bp = W0; bias = b0; out = out0; ldb = 1024; n0 = y*128; ldout = 1024; scale = 0.125f; }
    else if (y == 8){ Bp = W1; bias = b1; out = out1; ldb = 128;  n0 = 0;     ldout = 128; }
    else            { Bp = W2; bias = b2; out = out2; ldb = 128;  n0 = 0;     ldout = 128; }
  } else            { Bp = W0; bias = b0; out = out0; ldb = 1024; n0 = y*128; ldout = 1024; }
  __shared__ float As[16][128];
  __shared__ float Bs[16][128];
  int tid = threadIdx.x;
  int tx = tid & 15, ty = tid >> 4;
  float acc[2][2][4][4] = {};
  for (int kb = 0; kb < 1024; kb += 16) {
    __syncthreads();
    {
      int row = tid >> 2, c = tid & 3;
      #pragma unroll
      for (int i = 0; i < 2; i++) {
        int rr = row + i*64;
        float4 v = *(const float4*)&A[(size_t)(m0+rr)*1024 + kb + c*4];
        As[c*4+0][rr] = v.x; As[c*4+1][rr] = v.y; As[c*4+2][rr] = v.z; As[c*4+3][rr] = v.w;
      }
      #pragma unroll
      for (int i = 0; i < 2; i++) {
        int idx = tid + i*256;
        int kr = idx >> 5, c4 = idx & 31;
        *(float4*)&Bs[kr][c4*4] = *(const float4*)&Bp[(size_t)(kb+kr)*ldb + n0 + c4*4];
      }
    }
    __syncthreads();
    #pragma unroll
    for (int k = 0; k < 16; k++) {
      float a0[4], a1[4], bb0[4], bb1[4];
      *(float4*)a0  = *(const float4*)&As[k][ty*4];
      *(float4*)a1  = *(const float4*)&As[k][64 + ty*4];
      *(float4*)bb0 = *(const float4*)&Bs[k][tx*4];
      *(float4*)bb1 = *(const float4*)&Bs[k][64 + tx*4];
      #pragma unroll
      for (int i = 0; i < 4; i++)
        #pragma unroll
        for (int j = 0; j < 4; j++) {
          acc[0][0][i][j] += a0[i]*bb0[j];
          acc[0][1][i][j] += a0[i]*bb1[j];
          acc[1][0][i][j] += a1[i]*bb0[j];
          acc[1][1][i][j] += a1[i]*bb1[j];
        }
    }
  }
  #pragma unroll
  for (int ib = 0; ib < 2; ib++)
    #pragma unroll
    for (int i = 0; i < 4; i++) {
      int row = m0 + ib*64 + ty*4 + i;
      #pragma unroll
      for (int jb = 0; jb < 2; jb++) {
        int col = n0 + jb*64 + tx*4;
        float4 v;
        v.x = acc[ib][jb][i][0] + bias[col+0];
        v.y = acc[ib][jb][i][1] + bias[col+1];
        v.z = acc[ib][jb][i][2] + bias[col+2];
        v.w = acc[ib][jb][i][3] + bias[col+3];
        if (MODE == 1) {
          const float4 rv = *(const float4*)&resid[(size_t)row*1024 + col];
          v.x += rv.x; v.y += rv.y; v.z += rv.z; v.w += rv.w;
        } else {
          v.x *= scale; v.y *= scale; v.z *= scale; v.w *= scale;
        }
        *(float4*)&out[(size_t)row*ldout + col] = v;
      }
    }
}

// ---------------- fp32 windowed attention ----------------
// Output row t=n*256+q uses query token n*128+q, keys [n*128, n*128+256). Head h uses KV group h&1.
// Q pre-scaled by 1/8. Thread = (query, hd-quarter). Online softmax, K/V LDS-staged per 128-key chunk.
__global__ __launch_bounds__(256) void attn_f32(
    const float* __restrict__ Qs, const float* __restrict__ Kf, const float* __restrict__ Vf,
    float* __restrict__ Ao) {
  int qb = blockIdx.x;          // 0..3
  int n  = blockIdx.y;          // 0..15
  int b  = blockIdx.z >> 4;
  int h  = blockIdx.z & 15;
  int g  = h & 1;
  int tid = threadIdx.x;
  int q = tid >> 2, hq = tid & 3;
  int qtok = b*4096 + n*128 + qb*64 + q;
  float qreg[16];
  #pragma unroll
  for (int t4 = 0; t4 < 4; t4++)
    *(float4*)&qreg[t4*4] = *(const float4*)&Qs[(size_t)qtok*1024 + h*64 + hq*16 + t4*4];
  __shared__ float Ks[128][64];
  __shared__ float Vs[128][64];
  float o[16] = {};
  float m = -1e30f, l = 0.f;
  for (int c = 0; c < 2; c++) {
    __syncthreads();
    int key0 = b*4096 + n*128 + c*128;
    #pragma unroll
    for (int i = 0; i < 8; i++) {
      int idx = tid + i*256;
      int key = idx >> 4, c4 = idx & 15;
      *(float4*)&Ks[key][c4*4] = *(const float4*)&Kf[(size_t)(key0+key)*128 + g*64 + c4*4];
      *(float4*)&Vs[key][c4*4] = *(const float4*)&Vf[(size_t)(key0+key)*128 + g*64 + c4*4];
    }
    __syncthreads();
    for (int k = 0; k < 128; k++) {
      float s = 0.f;
      #pragma unroll
      for (int j = 0; j < 16; j++) s += qreg[j] * Ks[k][hq*16+j];
      s += __shfl_xor(s, 1);
      s += __shfl_xor(s, 2);
      float mn = fmaxf(m, s);
      float corr = __expf(m - mn);
      float p = __expf(s - mn);
      l = l*corr + p;
      #pragma unroll
      for (int j = 0; j < 16; j++) o[j] = o[j]*corr + p*Vs[k][hq*16+j];
      m = mn;
    }
  }
  float inv = 1.f / l;
  int orow = b*4096 + n*256 + qb*64 + q;
  #pragma unroll
  for (int t4 = 0; t4 < 4; t4++) {
    float4 v = { o[t4*4]*inv, o[t4*4+1]*inv, o[t4*4+2]*inv, o[t4*4+3]*inv };
    *(float4*)&Ao[(size_t)orow*1024 + h*64 + hq*16 + t4*4] = v;
  }
}

// ---------------- gating (fp64 logits -> exact-as-possible top2) ----------------
__global__ __launch_bounds__(256) void gating_kernel(
    const float* __restrict__ h, const float* __restrict__ g2, const float* __restrict__ b2,
    const float* __restrict__ Wg, const float* __restrict__ bg,
    int* __restrict__ cnt, int* __restrict__ bucket, float* __restrict__ bucketP,
    int* __restrict__ bucketS, float* __restrict__ entPartial) {
  int tid = threadIdx.x, lane = tid & 63, wid = tid >> 6;
  int tok = blockIdx.x*4 + wid;
  const float* row = h + (size_t)tok * 1024;
  float xv[16];
  #pragma unroll
  for (int q = 0; q < 4; q++) *(float4*)&xv[q*4] = ((const float4*)row)[lane*4 + q];
  double s = 0.0, s2 = 0.0;
  #pragma unroll
  for (int j = 0; j < 16; j++) { double d = (double)xv[j]; s += d; s2 += d*d; }
  s = wave_sum64d(s); s2 = wave_sum64d(s2);
  double mu = s / 1024.0;
  double var = s2 / 1024.0 - mu*mu;
  double rs = 1.0 / sqrt(var + 1e-5);
  double acc[8] = {};
  #pragma unroll
  for (int q = 0; q < 4; q++) {
    #pragma unroll
    for (int j = 0; j < 4; j++) {
      int i = lane*16 + q*4 + j;
      double xn = ((double)xv[q*4+j] - mu) * rs * (double)g2[i] + (double)b2[i];
      const float4 w0 = *(const float4*)&Wg[(size_t)i*8];
      const float4 w1 = *(const float4*)&Wg[(size_t)i*8 + 4];
      acc[0] += xn*(double)w0.x; acc[1] += xn*(double)w0.y;
      acc[2] += xn*(double)w0.z; acc[3] += xn*(double)w0.w;
      acc[4] += xn*(double)w1.x; acc[5] += xn*(double)w1.y;
      acc[6] += xn*(double)w1.z; acc[7] += xn*(double)w1.w;
    }
  }
  #pragma unroll
  for (int e = 0; e < 8; e++) {
    acc[e] = wave_sum64d(acc[e]);
    acc[e] += (double)bg[e];
  }
  double mx = acc[0];
  #pragma unroll
  for (int e = 1; e < 8; e++) mx = acc[e] > mx ? acc[e] : mx;
  double ex[8], Z = 0.0;
  #pragma unroll
  for (int e = 0; e < 8; e++) { ex[e] = exp(acc[e] - mx); Z += ex[e]; }
  double invZ = 1.0 / Z;
  double ent = 0.0;
  double p[8];
  #pragma unroll
  for (int e = 0; e < 8; e++) { p[e] = ex[e]*invZ; ent -= p[e]*log(p[e] + 1e-8); }
  int e1 = 0;
  #pragma unroll
  for (int e = 1; e < 8; e++) if (acc[e] > acc[e1]) e1 = e;
  int e2 = (e1 == 0) ? 1 : 0;
  #pragma unroll
  for (int e = 0; e < 8; e++) if (e != e1 && acc[e] > acc[e2]) e2 = e;
  if (lane == 0) {
    int i1 = atomicAdd(&cnt[e1], 1);
    bucket[e1*8192 + i1] = tok; bucketP[e1*8192 + i1] = (float)p[e1]; bucketS[e1*8192 + i1] = 0;
    int i2 = atomicAdd(&cnt[e2], 1);
    bucket[e2*8192 + i2] = tok; bucketP[e2*8192 + i2] = (float)p[e2]; bucketS[e2*8192 + i2] = 1;
  }
  __shared__ float eb[4];
  if (lane == 0) eb[wid] = (float)ent;
  __syncthreads();
  if (tid == 0) entPartial[blockIdx.x] = eb[0]+eb[1]+eb[2]+eb[3];
}

__global__ __launch_bounds__(256) void aux_kernel(const float* __restrict__ entPartial,
    const int* __restrict__ cnt, float* __restrict__ auxOut) {
  int tid = threadIdx.x;
  float s = 0.f;
  for (int i = tid; i < 2048; i += 256) s += entPartial[i];
  s = wave_sum64(s);
  __shared__ float pa[4];
  if ((tid & 63) == 0) pa[tid >> 6] = s;
  __syncthreads();
  if (tid == 0) {
    float tot = pa[0]+pa[1]+pa[2]+pa[3];
    float entMean = tot / 8192.f;
    float pen = 0.f;
    for (int e = 0; e < 8; e++) {
      float usage = (float)cnt[e] / (8192.f + 1e-8f);
      pen += fmaxf(usage - 0.4f, 0.f);
    }
    auxOut[0] = 0.05f * entMean + pen;
  }
}

// ---------------- We transpose (fp32 -> bf16, per expert) ----------------
__global__ void transpose_We(const float* __restrict__ We, short* __restrict__ WeT) {
  int e = blockIdx.z;
  __shared__ float tile[32][33];
  int kt = blockIdx.x, nt = blockIdx.y;
  int tx = threadIdx.x, ty = threadIdx.y;
  const float* src = We + (size_t)e * 1048576;
  short* dst = WeT + (size_t)e * 1048576;
  #pragma unroll
  for (int i = 0; i < 4; i++)
    tile[ty + 8*i][tx] = src[(size_t)(kt*32 + ty + 8*i)*1024 + nt*32 + tx];
  __syncthreads();
  #pragma unroll
  for (int i = 0; i < 4; i++)
    dst[(size_t)(nt*32 + ty + 8*i)*1024 + kt*32 + tx] = f2bf(tile[tx][ty + 8*i]);
}

// ---------------- bf16 MFMA grouped MoE GEMM ----------------
// Per block: expert e, 128 gathered token rows, 128 hid cols. Writes p*(x@We+be) into slot buf.
__global__ __launch_bounds__(256) void moe_gemm(
    const short* __restrict__ hln, const short* __restrict__ WeT,
    const float* __restrict__ be, const int* __restrict__ cnt,
    const int* __restrict__ bucket, const float* __restrict__ bucketP,
    const int* __restrict__ bucketS,
    float* __restrict__ slot0, float* __restrict__ slot1) {
  int e = blockIdx.z;
  int count = cnt[e];
  int mtile = blockIdx.x;
  if (mtile * 128 >= count) return;
  int n0 = blockIdx.y * 128;
  __shared__ short As[128*72];
  __shared__ short Bs[128*72];
  __shared__ int   toks[128];
  __shared__ float pws[128];
  __shared__ int   sls[128];
  int tid = threadIdx.x;
  if (tid < 128) {
    int idx = mtile*128 + tid;
    int ic = idx < count ? idx : count - 1;
    toks[tid] = bucket[e*8192 + ic];
    pws[tid]  = bucketP[e*8192 + ic];
    sls[tid]  = bucketS[e*8192 + ic];
  }
  __syncthreads();
  int mytok[4];
  #pragma unroll
  for (int i = 0; i < 4; i++) mytok[i] = toks[(tid + 256*i) >> 3];
  const short* Bt = WeT + (size_t)e * 1048576;
  int lane = tid & 63, wid = tid >> 6;
  int wm = (wid & 1) * 64, wn = (wid >> 1) * 64;
  int l15 = lane & 15, quad = lane >> 4;
  f32x4 acc[4][4] = {};
  for (int kb = 0; kb < 1024; kb += 64) {
    __syncthreads();
    #pragma unroll
    for (int i = 0; i < 4; i++) {
      int c = tid + 256*i;
      int row = c >> 3, cb = c & 7;
      *(uint4*)&As[row*72 + cb*8] = *(const uint4*)&hln[(size_t)mytok[i]*1024 + kb + cb*8];
      *(uint4*)&Bs[row*72 + cb*8] = *(const uint4*)&Bt[(size_t)(n0+row)*1024 + kb + cb*8];
    }
    __syncthreads();
    #pragma unroll
    for (int ks = 0; ks < 2; ks++) {
      bf16x8 af[4], bfr[4];
      #pragma unroll
      for (int mt = 0; mt < 4; mt++)
        af[mt] = *(const bf16x8*)&As[(wm + mt*16 + l15)*72 + ks*32 + quad*8];
      #pragma unroll
      for (int nt = 0; nt < 4; nt++)
        bfr[nt] = *(const bf16x8*)&Bs[(wn + nt*16 + l15)*72 + ks*32 + quad*8];
      #pragma unroll
      for (int mt = 0; mt < 4; mt++)
        #pragma unroll
        for (int nt = 0; nt < 4; nt++)
          acc[mt][nt] = __builtin_amdgcn_mfma_f32_16x16x32_bf16(af[mt], bfr[nt], acc[mt][nt], 0, 0, 0);
    }
  }
  #pragma unroll
  for (int mt = 0; mt < 4; mt++) {
    #pragma unroll
    for (int r = 0; r < 4; r++) {
      int m = wm + mt*16 + quad*4 + r;
      if (mtile*128 + m < count) {
        int tok = toks[m];
        float pp = pws[m];
        float* dst = sls[m] ? slot1 : slot0;
        #pragma unroll
        for (int nt = 0; nt < 4; nt++) {
          int col = n0 + wn + nt*16 + l15;
          dst[(size_t)tok*1024 + col] = pp * (acc[mt][nt][r] + be[e*1024 + col]);
        }
      }
    }
  }
}

// ---------------- final combine ----------------
__global__ __launch_bounds__(256) void final_add(float* __restrict__ out,
    const float* __restrict__ s0, const float* __restrict__ s1) {
  const int total = 8388608 / 4;
  for (int i = blockIdx.x*256 + threadIdx.x; i < total; i += gridDim.x*256) {
    float4 a = ((float4*)out)[i];
    const float4 x0 = ((const float4*)s0)[i];
    const float4 x1 = ((const float4*)s1)[i];
    a.x += x0.x + x1.x; a.y += x0.y + x1.y; a.z += x0.z + x1.z; a.w += x0.w + x1.w;
    ((float4*)out)[i] = a;
  }
}

// ---------------- host launcher ----------------
extern "C" void kernel_launch(void* const* d_in, const int* in_sizes, int n_in,
                              void* d_out, int out_size, void* d_ws, size_t ws_size,
                              hipStream_t stream) {
  const float* x    = (const float*)d_in[0];
  const float* Wq   = (const float*)d_in[1];
  const float* bq   = (const float*)d_in[2];
  const float* Wk   = (const float*)d_in[3];
  const float* bk   = (const float*)d_in[4];
  const float* Wv   = (const float*)d_in[5];
  const float* bv   = (const float*)d_in[6];
  const float* Wo   = (const float*)d_in[7];
  const float* bo   = (const float*)d_in[8];
  const float* ln1g = (const float*)d_in[9];
  const float* ln1b = (const float*)d_in[10];
  const float* ln2g = (const float*)d_in[11];
  const float* ln2b = (const float*)d_in[12];
  const float* Wg   = (const float*)d_in[13];
  const float* bg   = (const float*)d_in[14];
  const float* We   = (const float*)d_in[15];
  const float* be   = (const float*)d_in[16];
  float* out = (float*)d_out;

  char* ws = (char*)d_ws;
  size_t off = 0;
  auto alloc = [&](size_t bytes) { char* p = ws + off; off += (bytes + 255) & ~(size_t)255; return p; };
  float* xln   = (float*)alloc(33554432);   // 8192x1024 f32; reused as attn_out
  float* Qs    = (float*)alloc(33554432);   // 8192x1024 f32 (pre-scaled 1/8); reused as hln region
  float* Kf    = (float*)alloc(4194304);    // 8192x128 f32
  float* Vf    = (float*)alloc(4194304);    // 8192x128 f32
  short* WeT   = (short*)alloc(16777216);   // 8x1024x1024 bf16 (transposed per expert)
  float* slot0 = (float*)alloc(33554432);
  float* slot1 = (float*)alloc(33554432);
  int*   bucket  = (int*)alloc(262144);
  float* bucketP = (float*)alloc(262144);
  int*   bucketS = (int*)alloc(262144);
  int*   cnt     = (int*)alloc(256);
  float* entPartial = (float*)alloc(8192);
  float* attn_out = xln;       // alias: xln dead after QKV GEMM
  short* hln      = (short*)Qs; // alias: Qs dead after attention

  hipMemsetAsync(cnt, 0, 256, stream);
  transpose_We<<<dim3(32,32,8), dim3(32,8), 0, stream>>>(We, WeT);
  ln_f32<<<8192, 256, 0, stream>>>(x, ln1g, ln1b, xln);
  gemm_f32<0><<<dim3(64,10), 256, 0, stream>>>(xln, Wq, Wk, Wv, bq, bk, bv, nullptr, Qs, Kf, Vf);
  attn_f32<<<dim3(4,16,32), 256, 0, stream>>>(Qs, Kf, Vf, attn_out);
  gemm_f32<1><<<dim3(64,8), 256, 0, stream>>>(attn_out, Wo, nullptr, nullptr, bo, nullptr, nullptr,
                                              x, out, nullptr, nullptr);
  ln_bf16<<<8192, 256, 0, stream>>>(out, ln2g, ln2b, hln);
  gating_kernel<<<2048, 256, 0, stream>>>(out, ln2g, ln2b, Wg, bg,
                                          cnt, bucket, bucketP, bucketS, entPartial);
  aux_kernel<<<1, 256, 0, stream>>>(entPartial, cnt, out + 8388608);
  moe_gemm<<<dim3(64,8,8), 256, 0, stream>>>(hln, WeT, be, cnt, bucket, bucketP, bucketS, slot0, slot1);
  final_add<<<2048, 256, 0, stream>>>(out, slot0, slot1);
}

// Round 2
// 984.793 us; speedup vs baseline: 1.2686x; 1.2686x over previous
//
#include <hip/hip_runtime.h>
#include <hip/hip_bf16.h>
#include <stdint.h>

// ---------------- types / helpers ----------------
typedef __attribute__((ext_vector_type(8))) short bf16x8;
typedef __attribute__((ext_vector_type(8))) _Float16 f16x8;
typedef __attribute__((ext_vector_type(4))) _Float16 f16x4;
typedef __attribute__((ext_vector_type(4))) float f32x4;

__device__ __forceinline__ short f2bf(float f) {
  __hip_bfloat16 h = __float2bfloat16(f);
  union { __hip_bfloat16 h; short s; } u; u.h = h; return u.s;
}

__device__ __forceinline__ float wave_sum64(float v) {
  #pragma unroll
  for (int off = 1; off < 64; off <<= 1) v += __shfl_xor(v, off);
  return v;
}
__device__ __forceinline__ double wave_sum64d(double v) {
  #pragma unroll
  for (int off = 1; off < 64; off <<= 1) v += __shfl_xor(v, off);
  return v;
}

// ---------------- LN kernels ----------------
__global__ __launch_bounds__(256) void ln_f32(const float* __restrict__ x,
    const float* __restrict__ g, const float* __restrict__ b, float* __restrict__ out) {
  int t = blockIdx.x, tid = threadIdx.x;
  const float4 v = ((const float4*)(x + (size_t)t * 1024))[tid];
  float s = v.x + v.y + v.z + v.w;
  float s2 = v.x*v.x + v.y*v.y + v.z*v.z + v.w*v.w;
  s = wave_sum64(s); s2 = wave_sum64(s2);
  __shared__ float pa[4], pb[4];
  int wid = tid >> 6, lane = tid & 63;
  if (lane == 0) { pa[wid] = s; pb[wid] = s2; }
  __syncthreads();
  float S = pa[0]+pa[1]+pa[2]+pa[3], S2 = pb[0]+pb[1]+pb[2]+pb[3];
  float mu = S * (1.f/1024.f);
  float var = S2 * (1.f/1024.f) - mu*mu;
  float rs = rsqrtf(var + 1e-5f);
  const float4 gv = ((const float4*)g)[tid];
  const float4 bv = ((const float4*)b)[tid];
  float4 o;
  o.x = (v.x-mu)*rs*gv.x + bv.x; o.y = (v.y-mu)*rs*gv.y + bv.y;
  o.z = (v.z-mu)*rs*gv.z + bv.z; o.w = (v.w-mu)*rs*gv.w + bv.w;
  ((float4*)(out + (size_t)t * 1024))[tid] = o;
}

__global__ __launch_bounds__(256) void ln_bf16(const float* __restrict__ x,
    const float* __restrict__ g, const float* __restrict__ b, short* __restrict__ out) {
  int t = blockIdx.x, tid = threadIdx.x;
  const float4 v = ((const float4*)(x + (size_t)t * 1024))[tid];
  float s = v.x + v.y + v.z + v.w;
  float s2 = v.x*v.x + v.y*v.y + v.z*v.z + v.w*v.w;
  s = wave_sum64(s); s2 = wave_sum64(s2);
  __shared__ float pa[4], pb[4];
  int wid = tid >> 6, lane = tid & 63;
  if (lane == 0) { pa[wid] = s; pb[wid] = s2; }
  __syncthreads();
  float S = pa[0]+pa[1]+pa[2]+pa[3], S2 = pb[0]+pb[1]+pb[2]+pb[3];
  float mu = S * (1.f/1024.f);
  float var = S2 * (1.f/1024.f) - mu*mu;
  float rs = rsqrtf(var + 1e-5f);
  const float4 gv = ((const float4*)g)[tid];
  const float4 bv = ((const float4*)b)[tid];
  short4 o;
  o.x = f2bf((v.x-mu)*rs*gv.x + bv.x); o.y = f2bf((v.y-mu)*rs*gv.y + bv.y);
  o.z = f2bf((v.z-mu)*rs*gv.z + bv.z); o.w = f2bf((v.w-mu)*rs*gv.w + bv.w);
  ((short4*)(out + (size_t)t * 1024))[tid] = o;
}

// ---------------- weight transpose + fp16 hi/lo split ----------------
// dst[n][k] (hi,lo*2048 as fp16) from src[k][n], K=1024, n in [0,srcN)
__global__ void t_w_f16(const float* __restrict__ src, int srcN,
                        _Float16* __restrict__ dh, _Float16* __restrict__ dl, int dstRow0) {
  __shared__ float tile[32][33];
  int kt = blockIdx.x, nt = blockIdx.y;
  int tx = threadIdx.x, ty = threadIdx.y;
  #pragma unroll
  for (int i = 0; i < 4; i++)
    tile[ty + 8*i][tx] = src[(size_t)(kt*32 + ty + 8*i)*srcN + nt*32 + tx];
  __syncthreads();
  #pragma unroll
  for (int i = 0; i < 4; i++) {
    float v = tile[tx][ty + 8*i];
    _Float16 h = (_Float16)v;
    _Float16 l = (_Float16)((v - (float)h) * 2048.0f);
    size_t o = (size_t)(dstRow0 + nt*32 + ty + 8*i)*1024 + kt*32 + tx;
    dh[o] = h; dl[o] = l;
  }
}

// ---------------- split-fp16 MFMA GEMM (precision-critical path) ----------------
// C[M x N] = A[M x 1024] @ B, B pre-transposed/split: BT[n][k] hi/lo.
// C = accM + accC/2048, accM = hi*hi, accC = hi*lo + lo*hi (lo*lo dropped, ~2^-22 rel).
// MODE 0: fused QKV (y 0..7 -> Q cols y*128 scaled 1/8; y==8 -> K; y==9 -> V)
// MODE 1: Wo + bias + residual -> fp32 out (h)
template<int MODE>
__global__ __launch_bounds__(256) void gemm_f16x2(
    const float* __restrict__ A,
    const _Float16* __restrict__ BTh, const _Float16* __restrict__ BTl,
    const float* __restrict__ b0, const float* __restrict__ b1, const float* __restrict__ b2,
    const float* __restrict__ resid,
    float* __restrict__ out0, float* __restrict__ out1, float* __restrict__ out2) {
  int m0 = blockIdx.x * 128;
  int y = blockIdx.y;
  int n0 = y * 128;                 // row offset into BT
  float* dst; const float* biasp; int dcol0, ld; float scale = 1.f;
  if (MODE == 0) {
    if (y < 8)      { dst = out0; biasp = b0 + y*128; dcol0 = y*128; ld = 1024; scale = 0.125f; }
    else if (y == 8){ dst = out1; biasp = b1; dcol0 = 0; ld = 128; }
    else            { dst = out2; biasp = b2; dcol0 = 0; ld = 128; }
  } else            { dst = out0; biasp = b0 + y*128; dcol0 = y*128; ld = 1024; }

  __shared__ _Float16 Ah[128*72];
  __shared__ _Float16 Al[128*72];
  __shared__ _Float16 Bh[128*72];
  __shared__ _Float16 Bl[128*72];
  int tid = threadIdx.x;
  int lane = tid & 63, wid = tid >> 6;
  int wm = (wid & 1) * 64, wn = (wid >> 1) * 64;
  int l15 = lane & 15, quad = lane >> 4;
  f32x4 accM[4][4] = {};
  f32x4 accC[4][4] = {};
  for (int kb = 0; kb < 1024; kb += 64) {
    __syncthreads();
    #pragma unroll
    for (int i = 0; i < 8; i++) {
      int idx = tid + 256*i;
      int row = idx >> 4, c4 = idx & 15;
      float4 v = *(const float4*)&A[(size_t)(m0+row)*1024 + kb + c4*4];
      f16x4 hv, lv;
      hv.x = (_Float16)v.x; lv.x = (_Float16)((v.x - (float)hv.x) * 2048.f);
      hv.y = (_Float16)v.y; lv.y = (_Float16)((v.y - (float)hv.y) * 2048.f);
      hv.z = (_Float16)v.z; lv.z = (_Float16)((v.z - (float)hv.z) * 2048.f);
      hv.w = (_Float16)v.w; lv.w = (_Float16)((v.w - (float)hv.w) * 2048.f);
      *(f16x4*)&Ah[row*72 + c4*4] = hv;
      *(f16x4*)&Al[row*72 + c4*4] = lv;
    }
    #pragma unroll
    for (int i = 0; i < 4; i++) {
      int idx = tid + 256*i;
      int row = idx >> 3, c8 = idx & 7;
      *(uint4*)&Bh[row*72 + c8*8] = *(const uint4*)&BTh[(size_t)(n0+row)*1024 + kb + c8*8];
      *(uint4*)&Bl[row*72 + c8*8] = *(const uint4*)&BTl[(size_t)(n0+row)*1024 + kb + c8*8];
    }
    __syncthreads();
    #pragma unroll
    for (int ks = 0; ks < 2; ks++) {
      f16x8 ah[4], al[4], bh[4], bl[4];
      #pragma unroll
      for (int mt = 0; mt < 4; mt++) {
        ah[mt] = *(const f16x8*)&Ah[(wm + mt*16 + l15)*72 + ks*32 + quad*8];
        al[mt] = *(const f16x8*)&Al[(wm + mt*16 + l15)*72 + ks*32 + quad*8];
      }
      #pragma unroll
      for (int nt = 0; nt < 4; nt++) {
        bh[nt] = *(const f16x8*)&Bh[(wn + nt*16 + l15)*72 + ks*32 + quad*8];
        bl[nt] = *(const f16x8*)&Bl[(wn + nt*16 + l15)*72 + ks*32 + quad*8];
      }
      #pragma unroll
      for (int mt = 0; mt < 4; mt++)
        #pragma unroll
        for (int nt = 0; nt < 4; nt++) {
          accM[mt][nt] = __builtin_amdgcn_mfma_f32_16x16x32_f16(ah[mt], bh[nt], accM[mt][nt], 0, 0, 0);
          accC[mt][nt] = __builtin_amdgcn_mfma_f32_16x16x32_f16(ah[mt], bl[nt], accC[mt][nt], 0, 0, 0);
          accC[mt][nt] = __builtin_amdgcn_mfma_f32_16x16x32_f16(al[mt], bh[nt], accC[mt][nt], 0, 0, 0);
        }
    }
  }
  const float inv2048 = 1.0f / 2048.0f;
  #pragma unroll
  for (int mt = 0; mt < 4; mt++)
    #pragma unroll
    for (int r = 0; r < 4; r++) {
      int row = m0 + wm + mt*16 + quad*4 + r;
      #pragma unroll
      for (int nt = 0; nt < 4; nt++) {
        int c = wn + nt*16 + l15;
        float v = accM[mt][nt][r] + accC[mt][nt][r]*inv2048 + biasp[c];
        if (MODE == 1) v += resid[(size_t)row*1024 + dcol0 + c];
        else v *= scale;
        dst[(size_t)row*ld + dcol0 + c] = v;
      }
    }
}

// ---------------- fp32 windowed attention ----------------
__global__ __launch_bounds__(256) void attn_f32(
    const float* __restrict__ Qs, const float* __restrict__ Kf, const float* __restrict__ Vf,
    float* __restrict__ Ao) {
  int qb = blockIdx.x;          // 0..3
  int n  = blockIdx.y;          // 0..15
  int b  = blockIdx.z >> 4;
  int h  = blockIdx.z & 15;
  int g  = h & 1;
  int tid = threadIdx.x;
  int q = tid >> 2, hq = tid & 3;
  int qtok = b*4096 + n*128 + qb*64 + q;
  float qreg[16];
  #pragma unroll
  for (int t4 = 0; t4 < 4; t4++)
    *(float4*)&qreg[t4*4] = *(const float4*)&Qs[(size_t)qtok*1024 + h*64 + hq*16 + t4*4];
  __shared__ float Ks[128][64];
  __shared__ float Vs[128][64];
  float o[16] = {};
  float m = -1e30f, l = 0.f;
  for (int c = 0; c < 2; c++) {
    __syncthreads();
    int key0 = b*4096 + n*128 + c*128;
    #pragma unroll
    for (int i = 0; i < 8; i++) {
      int idx = tid + i*256;
      int key = idx >> 4, c4 = idx & 15;
      *(float4*)&Ks[key][c4*4] = *(const float4*)&Kf[(size_t)(key0+key)*128 + g*64 + c4*4];
      *(float4*)&Vs[key][c4*4] = *(const float4*)&Vf[(size_t)(key0+key)*128 + g*64 + c4*4];
    }
    __syncthreads();
    for (int k = 0; k < 128; k++) {
      float s = 0.f;
      #pragma unroll
      for (int j = 0; j < 16; j++) s += qreg[j] * Ks[k][hq*16+j];
      s += __shfl_xor(s, 1);
      s += __shfl_xor(s, 2);
      float mn = fmaxf(m, s);
      float corr = __expf(m - mn);
      float p = __expf(s - mn);
      l = l*corr + p;
      #pragma unroll
      for (int j = 0; j < 16; j++) o[j] = o[j]*corr + p*Vs[k][hq*16+j];
      m = mn;
    }
  }
  float inv = 1.f / l;
  int orow = b*4096 + n*256 + qb*64 + q;
  #pragma unroll
  for (int t4 = 0; t4 < 4; t4++) {
    float4 v = { o[t4*4]*inv, o[t4*4+1]*inv, o[t4*4+2]*inv, o[t4*4+3]*inv };
    *(float4*)&Ao[(size_t)orow*1024 + h*64 + hq*16 + t4*4] = v;
  }
}

// ---------------- gating (fp64 logits) ----------------
__global__ __launch_bounds__(256) void gating_kernel(
    const float* __restrict__ h, const float* __restrict__ g2, const float* __restrict__ b2,
    const float* __restrict__ Wg, const float* __restrict__ bg,
    int* __restrict__ cnt, int* __restrict__ bucket, float* __restrict__ bucketP,
    int* __restrict__ bucketS, float* __restrict__ entPartial) {
  int tid = threadIdx.x, lane = tid & 63, wid = tid >> 6;
  int tok = blockIdx.x*4 + wid;
  const float* row = h + (size_t)tok * 1024;
  float xv[16];
  #pragma unroll
  for (int q = 0; q < 4; q++) *(float4*)&xv[q*4] = ((const float4*)row)[lane*4 + q];
  double s = 0.0, s2 = 0.0;
  #pragma unroll
  for (int j = 0; j < 16; j++) { double d = (double)xv[j]; s += d; s2 += d*d; }
  s = wave_sum64d(s); s2 = wave_sum64d(s2);
  double mu = s / 1024.0;
  double var = s2 / 1024.0 - mu*mu;
  double rs = 1.0 / sqrt(var + 1e-5);
  double acc[8] = {};
  #pragma unroll
  for (int q = 0; q < 4; q++) {
    #pragma unroll
    for (int j = 0; j < 4; j++) {
      int i = lane*16 + q*4 + j;
      double xn = ((double)xv[q*4+j] - mu) * rs * (double)g2[i] + (double)b2[i];
      const float4 w0 = *(const float4*)&Wg[(size_t)i*8];
      const float4 w1 = *(const float4*)&Wg[(size_t)i*8 + 4];
      acc[0] += xn*(double)w0.x; acc[1] += xn*(double)w0.y;
      acc[2] += xn*(double)w0.z; acc[3] += xn*(double)w0.w;
      acc[4] += xn*(double)w1.x; acc[5] += xn*(double)w1.y;
      acc[6] += xn*(double)w1.z; acc[7] += xn*(double)w1.w;
    }
  }
  #pragma unroll
  for (int e = 0; e < 8; e++) {
    acc[e] = wave_sum64d(acc[e]);
    acc[e] += (double)bg[e];
  }
  double mx = acc[0];
  #pragma unroll
  for (int e = 1; e < 8; e++) mx = acc[e] > mx ? acc[e] : mx;
  double ex[8], Z = 0.0;
  #pragma unroll
  for (int e = 0; e < 8; e++) { ex[e] = exp(acc[e] - mx); Z += ex[e]; }
  double invZ = 1.0 / Z;
  double ent = 0.0;
  double p[8];
  #pragma unroll
  for (int e = 0; e < 8; e++) { p[e] = ex[e]*invZ; ent -= p[e]*log(p[e] + 1e-8); }
  int e1 = 0;
  #pragma unroll
  for (int e = 1; e < 8; e++) if (acc[e] > acc[e1]) e1 = e;
  int e2 = (e1 == 0) ? 1 : 0;
  #pragma unroll
  for (int e = 0; e < 8; e++) if (e != e1 && acc[e] > acc[e2]) e2 = e;
  if (lane == 0) {
    int i1 = atomicAdd(&cnt[e1], 1);
    bucket[e1*8192 + i1] = tok; bucketP[e1*8192 + i1] = (float)p[e1]; bucketS[e1*8192 + i1] = 0;
    int i2 = atomicAdd(&cnt[e2], 1);
    bucket[e2*8192 + i2] = tok; bucketP[e2*8192 + i2] = (float)p[e2]; bucketS[e2*8192 + i2] = 1;
  }
  __shared__ float eb[4];
  if (lane == 0) eb[wid] = (float)ent;
  __syncthreads();
  if (tid == 0) entPartial[blockIdx.x] = eb[0]+eb[1]+eb[2]+eb[3];
}

__global__ __launch_bounds__(256) void aux_kernel(const float* __restrict__ entPartial,
    const int* __restrict__ cnt, float* __restrict__ auxOut) {
  int tid = threadIdx.x;
  float s = 0.f;
  for (int i = tid; i < 2048; i += 256) s += entPartial[i];
  s = wave_sum64(s);
  __shared__ float pa[4];
  if ((tid & 63) == 0) pa[tid >> 6] = s;
  __syncthreads();
  if (tid == 0) {
    float tot = pa[0]+pa[1]+pa[2]+pa[3];
    float entMean = tot / 8192.f;
    float pen = 0.f;
    for (int e = 0; e < 8; e++) {
      float usage = (float)cnt[e] / (8192.f + 1e-8f);
      pen += fmaxf(usage - 0.4f, 0.f);
    }
    auxOut[0] = 0.05f * entMean + pen;
  }
}

// ---------------- We transpose (fp32 -> bf16, per expert) ----------------
__global__ void transpose_We(const float* __restrict__ We, short* __restrict__ WeT) {
  int e = blockIdx.z;
  __shared__ float tile[32][33];
  int kt = blockIdx.x, nt = blockIdx.y;
  int tx = threadIdx.x, ty = threadIdx.y;
  const float* src = We + (size_t)e * 1048576;
  short* dst = WeT + (size_t)e * 1048576;
  #pragma unroll
  for (int i = 0; i < 4; i++)
    tile[ty + 8*i][tx] = src[(size_t)(kt*32 + ty + 8*i)*1024 + nt*32 + tx];
  __syncthreads();
  #pragma unroll
  for (int i = 0; i < 4; i++)
    dst[(size_t)(nt*32 + ty + 8*i)*1024 + kt*32 + tx] = f2bf(tile[tx][ty + 8*i]);
}

// ---------------- bf16 MFMA grouped MoE GEMM ----------------
__global__ __launch_bounds__(256) void moe_gemm(
    const short* __restrict__ hln, const short* __restrict__ WeT,
    const float* __restrict__ be, const int* __restrict__ cnt,
    const int* __restrict__ bucket, const float* __restrict__ bucketP,
    const int* __restrict__ bucketS,
    float* __restrict__ slot0, float* __restrict__ slot1) {
  int e = blockIdx.z;
  int count = cnt[e];
  int mtile = blockIdx.x;
  if (mtile * 128 >= count) return;
  int n0 = blockIdx.y * 128;
  __shared__ short As[128*72];
  __shared__ short Bs[128*72];
  __shared__ int   toks[128];
  __shared__ float pws[128];
  __shared__ int   sls[128];
  int tid = threadIdx.x;
  if (tid < 128) {
    int idx = mtile*128 + tid;
    int ic = idx < count ? idx : count - 1;
    toks[tid] = bucket[e*8192 + ic];
    pws[tid]  = bucketP[e*8192 + ic];
    sls[tid]  = bucketS[e*8192 + ic];
  }
  __syncthreads();
  int mytok[4];
  #pragma unroll
  for (int i = 0; i < 4; i++) mytok[i] = toks[(tid + 256*i) >> 3];
  const short* Bt = WeT + (size_t)e * 1048576;
  int lane = tid & 63, wid = tid >> 6;
  int wm = (wid & 1) * 64, wn = (wid >> 1) * 64;
  int l15 = lane & 15, quad = lane >> 4;
  f32x4 acc[4][4] = {};
  for (int kb = 0; kb < 1024; kb += 64) {
    __syncthreads();
    #pragma unroll
    for (int i = 0; i < 4; i++) {
      int c = tid + 256*i;
      int row = c >> 3, cb = c & 7;
      *(uint4*)&As[row*72 + cb*8] = *(const uint4*)&hln[(size_t)mytok[i]*1024 + kb + cb*8];
      *(uint4*)&Bs[row*72 + cb*8] = *(const uint4*)&Bt[(size_t)(n0+row)*1024 + kb + cb*8];
    }
    __syncthreads();
    #pragma unroll
    for (int ks = 0; ks < 2; ks++) {
      bf16x8 af[4], bfr[4];
      #pragma unroll
      for (int mt = 0; mt < 4; mt++)
        af[mt] = *(const bf16x8*)&As[(wm + mt*16 + l15)*72 + ks*32 + quad*8];
      #pragma unroll
      for (int nt = 0; nt < 4; nt++)
        bfr[nt] = *(const bf16x8*)&Bs[(wn + nt*16 + l15)*72 + ks*32 + quad*8];
      #pragma unroll
      for (int mt = 0; mt < 4; mt++)
        #pragma unroll
        for (int nt = 0; nt < 4; nt++)
          acc[mt][nt] = __builtin_amdgcn_mfma_f32_16x16x32_bf16(af[mt], bfr[nt], acc[mt][nt], 0, 0, 0);
    }
  }
  #pragma unroll
  for (int mt = 0; mt < 4; mt++) {
    #pragma unroll
    for (int r = 0; r < 4; r++) {
      int m = wm + mt*16 + quad*4 + r;
      if (mtile*128 + m < count) {
        int tok = toks[m];
        float pp = pws[m];
        float* dst = sls[m] ? slot1 : slot0;
        #pragma unroll
        for (int nt = 0; nt < 4; nt++) {
          int col = n0 + wn + nt*16 + l15;
          dst[(size_t)tok*1024 + col] = pp * (acc[mt][nt][r] + be[e*1024 + col]);
        }
      }
    }
  }
}

// ---------------- final combine ----------------
__global__ __launch_bounds__(256) void final_add(float* __restrict__ out,
    const float* __restrict__ s0, const float* __restrict__ s1) {
  const int total = 8388608 / 4;
  for (int i = blockIdx.x*256 + threadIdx.x; i < total; i += gridDim.x*256) {
    float4 a = ((float4*)out)[i];
    const float4 x0 = ((const float4*)s0)[i];
    const float4 x1 = ((const float4*)s1)[i];
    a.x += x0.x + x1.x; a.y += x0.y + x1.y; a.z += x0.z + x1.z; a.w += x0.w + x1.w;
    ((float4*)out)[i] = a;
  }
}

// ---------------- host launcher ----------------
extern "C" void kernel_launch(void* const* d_in, const int* in_sizes, int n_in,
                              void* d_out, int out_size, void* d_ws, size_t ws_size,
                              hipStream_t stream) {
  const float* x    = (const float*)d_in[0];
  const float* Wq   = (const float*)d_in[1];
  const float* bq   = (const float*)d_in[2];
  const float* Wk   = (const float*)d_in[3];
  const float* bk   = (const float*)d_in[4];
  const float* Wv   = (const float*)d_in[5];
  const float* bv   = (const float*)d_in[6];
  const float* Wo   = (const float*)d_in[7];
  const float* bo   = (const float*)d_in[8];
  const float* ln1g = (const float*)d_in[9];
  const float* ln1b = (const float*)d_in[10];
  const float* ln2g = (const float*)d_in[11];
  const float* ln2b = (const float*)d_in[12];
  const float* Wg   = (const float*)d_in[13];
  const float* bg   = (const float*)d_in[14];
  const float* We   = (const float*)d_in[15];
  const float* be   = (const float*)d_in[16];
  float* out = (float*)d_out;

  char* ws = (char*)d_ws;
  size_t off = 0;
  auto alloc = [&](size_t bytes) { char* p = ws + off; off += (bytes + 255) & ~(size_t)255; return p; };
  float* xln   = (float*)alloc(33554432);   // 8192x1024 f32; reused as attn_out
  float* Qs    = (float*)alloc(33554432);   // 8192x1024 f32 (Q pre-scaled 1/8); reused as hln
  float* Kf    = (float*)alloc(4194304);    // 8192x128 f32
  float* Vf    = (float*)alloc(4194304);    // 8192x128 f32
  short* WeT   = (short*)alloc(16777216);   // 8x1024x1024 bf16
  float* slot0 = (float*)alloc(33554432);
  float* slot1 = (float*)alloc(33554432);
  int*   bucket  = (int*)alloc(262144);
  float* bucketP = (float*)alloc(262144);
  int*   bucketS = (int*)alloc(262144);
  int*   cnt     = (int*)alloc(256);
  float* entPartial = (float*)alloc(8192);
  float* attn_out = xln;        // alias: xln dead after QKV GEMM
  short* hln      = (short*)Qs; // alias: Qs dead after attention
  // Weight hi/lo splits alias slot0/slot1 (dead until moe_gemm overwrites them):
  _Float16* WoTh    = (_Float16*)slot0;                  // 1024x1024 fp16 = 2 MB
  _Float16* WoTl    = (_Float16*)(slot0 + 1048576/2*1); // +2 MB (float* arith: 524288 floats)
  _Float16* BTqkv_h = (_Float16*)slot1;                  // 1280x1024 fp16 = 2.5 MB
  _Float16* BTqkv_l = (_Float16*)((char*)slot1 + 2621440);

  hipMemsetAsync(cnt, 0, 256, stream);
  // weight prep (per call; tiny)
  t_w_f16<<<dim3(32, 32), dim3(32, 8), 0, stream>>>(Wq, 1024, BTqkv_h, BTqkv_l, 0);
  t_w_f16<<<dim3(32, 4),  dim3(32, 8), 0, stream>>>(Wk, 128,  BTqkv_h, BTqkv_l, 1024);
  t_w_f16<<<dim3(32, 4),  dim3(32, 8), 0, stream>>>(Wv, 128,  BTqkv_h, BTqkv_l, 1152);
  t_w_f16<<<dim3(32, 32), dim3(32, 8), 0, stream>>>(Wo, 1024, WoTh, WoTl, 0);
  transpose_We<<<dim3(32,32,8), dim3(32,8), 0, stream>>>(We, WeT);

  ln_f32<<<8192, 256, 0, stream>>>(x, ln1g, ln1b, xln);
  gemm_f16x2<0><<<dim3(64,10), 256, 0, stream>>>(xln, BTqkv_h, BTqkv_l, bq, bk, bv,
                                                 nullptr, Qs, Kf, Vf);
  attn_f32<<<dim3(4,16,32), 256, 0, stream>>>(Qs, Kf, Vf, attn_out);
  gemm_f16x2<1><<<dim3(64,8), 256, 0, stream>>>(attn_out, WoTh, WoTl, bo, nullptr, nullptr,
                                                x, out, nullptr, nullptr);
  ln_bf16<<<8192, 256, 0, stream>>>(out, ln2g, ln2b, hln);
  gating_kernel<<<2048, 256, 0, stream>>>(out, ln2g, ln2b, Wg, bg,
                                          cnt, bucket, bucketP, bucketS, entPartial);
  aux_kernel<<<1, 256, 0, stream>>>(entPartial, cnt, out + 8388608);
  moe_gemm<<<dim3(64,8,8), 256, 0, stream>>>(hln, WeT, be, cnt, bucket, bucketP, bucketS, slot0, slot1);
  final_add<<<2048, 256, 0, stream>>>(out, slot0, slot1);
}

// Round 3
// 788.622 us; speedup vs baseline: 1.5841x; 1.2488x over previous
//
#include <hip/hip_runtime.h>
#include <hip/hip_bf16.h>
#include <stdint.h>

// ---------------- types / helpers ----------------
typedef __attribute__((ext_vector_type(8))) short bf16x8;
typedef __attribute__((ext_vector_type(8))) _Float16 f16x8;
typedef __attribute__((ext_vector_type(4))) _Float16 f16x4;
typedef __attribute__((ext_vector_type(4))) float f32x4;

__device__ __forceinline__ short f2bf(float f) {
  __hip_bfloat16 h = __float2bfloat16(f);
  union { __hip_bfloat16 h; short s; } u; u.h = h; return u.s;
}

__device__ __forceinline__ unsigned pk2(float a, float b) {
  union { _Float16 h; unsigned short s; } ua, ub;
  ua.h = (_Float16)a; ub.h = (_Float16)b;
  return (unsigned)ua.s | ((unsigned)ub.s << 16);
}

__device__ __forceinline__ float wave_sum64(float v) {
  #pragma unroll
  for (int off = 1; off < 64; off <<= 1) v += __shfl_xor(v, off);
  return v;
}
__device__ __forceinline__ double wave_sum64d(double v) {
  #pragma unroll
  for (int off = 1; off < 64; off <<= 1) v += __shfl_xor(v, off);
  return v;
}

// ---------------- LN kernels ----------------
__global__ __launch_bounds__(256) void ln_f32(const float* __restrict__ x,
    const float* __restrict__ g, const float* __restrict__ b, float* __restrict__ out) {
  int t = blockIdx.x, tid = threadIdx.x;
  const float4 v = ((const float4*)(x + (size_t)t * 1024))[tid];
  float s = v.x + v.y + v.z + v.w;
  float s2 = v.x*v.x + v.y*v.y + v.z*v.z + v.w*v.w;
  s = wave_sum64(s); s2 = wave_sum64(s2);
  __shared__ float pa[4], pb[4];
  int wid = tid >> 6, lane = tid & 63;
  if (lane == 0) { pa[wid] = s; pb[wid] = s2; }
  __syncthreads();
  float S = pa[0]+pa[1]+pa[2]+pa[3], S2 = pb[0]+pb[1]+pb[2]+pb[3];
  float mu = S * (1.f/1024.f);
  float var = S2 * (1.f/1024.f) - mu*mu;
  float rs = rsqrtf(var + 1e-5f);
  const float4 gv = ((const float4*)g)[tid];
  const float4 bv = ((const float4*)b)[tid];
  float4 o;
  o.x = (v.x-mu)*rs*gv.x + bv.x; o.y = (v.y-mu)*rs*gv.y + bv.y;
  o.z = (v.z-mu)*rs*gv.z + bv.z; o.w = (v.w-mu)*rs*gv.w + bv.w;
  ((float4*)(out + (size_t)t * 1024))[tid] = o;
}

__global__ __launch_bounds__(256) void ln_bf16(const float* __restrict__ x,
    const float* __restrict__ g, const float* __restrict__ b, short* __restrict__ out) {
  int t = blockIdx.x, tid = threadIdx.x;
  const float4 v = ((const float4*)(x + (size_t)t * 1024))[tid];
  float s = v.x + v.y + v.z + v.w;
  float s2 = v.x*v.x + v.y*v.y + v.z*v.z + v.w*v.w;
  s = wave_sum64(s); s2 = wave_sum64(s2);
  __shared__ float pa[4], pb[4];
  int wid = tid >> 6, lane = tid & 63;
  if (lane == 0) { pa[wid] = s; pb[wid] = s2; }
  __syncthreads();
  float S = pa[0]+pa[1]+pa[2]+pa[3], S2 = pb[0]+pb[1]+pb[2]+pb[3];
  float mu = S * (1.f/1024.f);
  float var = S2 * (1.f/1024.f) - mu*mu;
  float rs = rsqrtf(var + 1e-5f);
  const float4 gv = ((const float4*)g)[tid];
  const float4 bv = ((const float4*)b)[tid];
  short4 o;
  o.x = f2bf((v.x-mu)*rs*gv.x + bv.x); o.y = f2bf((v.y-mu)*rs*gv.y + bv.y);
  o.z = f2bf((v.z-mu)*rs*gv.z + bv.z); o.w = f2bf((v.w-mu)*rs*gv.w + bv.w);
  ((short4*)(out + (size_t)t * 1024))[tid] = o;
}

// ---------------- weight transpose + fp16 hi/lo split ----------------
__global__ void t_w_f16(const float* __restrict__ src, int srcN,
                        _Float16* __restrict__ dh, _Float16* __restrict__ dl, int dstRow0) {
  __shared__ float tile[32][33];
  int kt = blockIdx.x, nt = blockIdx.y;
  int tx = threadIdx.x, ty = threadIdx.y;
  #pragma unroll
  for (int i = 0; i < 4; i++)
    tile[ty + 8*i][tx] = src[(size_t)(kt*32 + ty + 8*i)*srcN + nt*32 + tx];
  __syncthreads();
  #pragma unroll
  for (int i = 0; i < 4; i++) {
    float v = tile[tx][ty + 8*i];
    _Float16 h = (_Float16)v;
    _Float16 l = (_Float16)((v - (float)h) * 2048.0f);
    size_t o = (size_t)(dstRow0 + nt*32 + ty + 8*i)*1024 + kt*32 + tx;
    dh[o] = h; dl[o] = l;
  }
}

// ---------------- split-fp16 MFMA GEMM ----------------
template<int MODE>
__global__ __launch_bounds__(256) void gemm_f16x2(
    const float* __restrict__ A,
    const _Float16* __restrict__ BTh, const _Float16* __restrict__ BTl,
    const float* __restrict__ b0, const float* __restrict__ b1, const float* __restrict__ b2,
    const float* __restrict__ resid,
    float* __restrict__ out0, float* __restrict__ out1, float* __restrict__ out2) {
  int m0 = blockIdx.x * 128;
  int y = blockIdx.y;
  int n0 = y * 128;
  float* dst; const float* biasp; int dcol0, ld;
  if (MODE == 0) {
    if (y < 8)      { dst = out0; biasp = b0 + y*128; dcol0 = y*128; ld = 1024; }
    else if (y == 8){ dst = out1; biasp = b1; dcol0 = 0; ld = 128; }
    else            { dst = out2; biasp = b2; dcol0 = 0; ld = 128; }
  } else            { dst = out0; biasp = b0 + y*128; dcol0 = y*128; ld = 1024; }

  __shared__ _Float16 Ah[128*72];
  __shared__ _Float16 Al[128*72];
  __shared__ _Float16 Bh[128*72];
  __shared__ _Float16 Bl[128*72];
  int tid = threadIdx.x;
  int lane = tid & 63, wid = tid >> 6;
  int wm = (wid & 1) * 64, wn = (wid >> 1) * 64;
  int l15 = lane & 15, quad = lane >> 4;
  f32x4 accM[4][4] = {};
  f32x4 accC[4][4] = {};
  for (int kb = 0; kb < 1024; kb += 64) {
    __syncthreads();
    #pragma unroll
    for (int i = 0; i < 8; i++) {
      int idx = tid + 256*i;
      int row = idx >> 4, c4 = idx & 15;
      float4 v = *(const float4*)&A[(size_t)(m0+row)*1024 + kb + c4*4];
      f16x4 hv, lv;
      hv.x = (_Float16)v.x; lv.x = (_Float16)((v.x - (float)hv.x) * 2048.f);
      hv.y = (_Float16)v.y; lv.y = (_Float16)((v.y - (float)hv.y) * 2048.f);
      hv.z = (_Float16)v.z; lv.z = (_Float16)((v.z - (float)hv.z) * 2048.f);
      hv.w = (_Float16)v.w; lv.w = (_Float16)((v.w - (float)hv.w) * 2048.f);
      *(f16x4*)&Ah[row*72 + c4*4] = hv;
      *(f16x4*)&Al[row*72 + c4*4] = lv;
    }
    #pragma unroll
    for (int i = 0; i < 4; i++) {
      int idx = tid + 256*i;
      int row = idx >> 3, c8 = idx & 7;
      *(uint4*)&Bh[row*72 + c8*8] = *(const uint4*)&BTh[(size_t)(n0+row)*1024 + kb + c8*8];
      *(uint4*)&Bl[row*72 + c8*8] = *(const uint4*)&BTl[(size_t)(n0+row)*1024 + kb + c8*8];
    }
    __syncthreads();
    #pragma unroll
    for (int ks = 0; ks < 2; ks++) {
      f16x8 ah[4], al[4], bh[4], bl[4];
      #pragma unroll
      for (int mt = 0; mt < 4; mt++) {
        ah[mt] = *(const f16x8*)&Ah[(wm + mt*16 + l15)*72 + ks*32 + quad*8];
        al[mt] = *(const f16x8*)&Al[(wm + mt*16 + l15)*72 + ks*32 + quad*8];
      }
      #pragma unroll
      for (int nt = 0; nt < 4; nt++) {
        bh[nt] = *(const f16x8*)&Bh[(wn + nt*16 + l15)*72 + ks*32 + quad*8];
        bl[nt] = *(const f16x8*)&Bl[(wn + nt*16 + l15)*72 + ks*32 + quad*8];
      }
      #pragma unroll
      for (int mt = 0; mt < 4; mt++)
        #pragma unroll
        for (int nt = 0; nt < 4; nt++) {
          accM[mt][nt] = __builtin_amdgcn_mfma_f32_16x16x32_f16(ah[mt], bh[nt], accM[mt][nt], 0, 0, 0);
          accC[mt][nt] = __builtin_amdgcn_mfma_f32_16x16x32_f16(ah[mt], bl[nt], accC[mt][nt], 0, 0, 0);
          accC[mt][nt] = __builtin_amdgcn_mfma_f32_16x16x32_f16(al[mt], bh[nt], accC[mt][nt], 0, 0, 0);
        }
    }
  }
  const float inv2048 = 1.0f / 2048.0f;
  #pragma unroll
  for (int mt = 0; mt < 4; mt++)
    #pragma unroll
    for (int r = 0; r < 4; r++) {
      int row = m0 + wm + mt*16 + quad*4 + r;
      #pragma unroll
      for (int nt = 0; nt < 4; nt++) {
        int c = wn + nt*16 + l15;
        float v = accM[mt][nt][r] + accC[mt][nt][r]*inv2048 + biasp[c];
        if (MODE == 1) v += resid[(size_t)row*1024 + dcol0 + c];
        dst[(size_t)row*ld + dcol0 + c] = v;
      }
    }
}

// ---------------- MFMA windowed attention ----------------
// Block: 64 queries (qb) x head h x window n x batch b. 4 waves x 16 queries.
// Split-fp16 QK^T (single-acc compensated), in-register softmax (x0.125),
// P f16 -> LDS, PV with f16 V^T. Q is NOT pre-scaled.
__global__ __launch_bounds__(256, 2) void attn_mfma(
    const float* __restrict__ Qs, const float* __restrict__ Kf, const float* __restrict__ Vf,
    float* __restrict__ Ao) {
  int qb = blockIdx.x, n = blockIdx.y;
  int b = blockIdx.z >> 4, h = blockIdx.z & 15;
  int g = h & 1;
  int tid = threadIdx.x;
  int lane = tid & 63, w = tid >> 6;
  int l15 = lane & 15, quad = lane >> 4;

  __shared__ __align__(16) char smem[70912];
  _Float16* Vt = (_Float16*)smem;                 // [64][264] f16 (V transposed)
  _Float16* Qh = (_Float16*)(smem + 33792);       // [64][72]
  _Float16* Ql = (_Float16*)(smem + 43008);       // [64][72]
  _Float16* Kh = (_Float16*)(smem + 52224);       // [64][72] chunk
  _Float16* Kl = (_Float16*)(smem + 61440);       // [64][72] chunk
  _Float16* Pm = (_Float16*)(smem + 33792);       // [64][264] alias over Q/K
  float*   linv = (float*)(smem + 70656);         // [64]

  int qtok0 = b*4096 + n*128 + qb*64;
  int key0  = b*4096 + n*128;

  // ---- stage Q (hi/lo, lo unscaled) ----
  #pragma unroll
  for (int i = 0; i < 4; i++) {
    int idx = tid + 256*i;
    int row = idx >> 4, c4 = idx & 15;
    float4 v = *(const float4*)&Qs[(size_t)(qtok0+row)*1024 + h*64 + c4*4];
    f16x4 hv, lv;
    hv.x = (_Float16)v.x; lv.x = (_Float16)(v.x - (float)hv.x);
    hv.y = (_Float16)v.y; lv.y = (_Float16)(v.y - (float)hv.y);
    hv.z = (_Float16)v.z; lv.z = (_Float16)(v.z - (float)hv.z);
    hv.w = (_Float16)v.w; lv.w = (_Float16)(v.w - (float)hv.w);
    *(f16x4*)&Qh[row*72 + c4*4] = hv;
    *(f16x4*)&Ql[row*72 + c4*4] = lv;
  }
  // ---- stage V transposed (plain f16) ----
  {
    int kk = tid >> 4, dd = tid & 15;
    #pragma unroll
    for (int i = 0; i < 8; i++) {
      int p = i*16 + kk;   // key pair 0..127
      float4 v0 = *(const float4*)&Vf[(size_t)(key0 + 2*p    )*128 + g*64 + dd*4];
      float4 v1 = *(const float4*)&Vf[(size_t)(key0 + 2*p + 1)*128 + g*64 + dd*4];
      *(unsigned*)&Vt[(dd*4+0)*264 + 2*p] = pk2(v0.x, v1.x);
      *(unsigned*)&Vt[(dd*4+1)*264 + 2*p] = pk2(v0.y, v1.y);
      *(unsigned*)&Vt[(dd*4+2)*264 + 2*p] = pk2(v0.z, v1.z);
      *(unsigned*)&Vt[(dd*4+3)*264 + 2*p] = pk2(v0.w, v1.w);
    }
  }
  __syncthreads();

  // ---- Q fragments to registers ----
  f16x8 qh[2], ql[2];
  {
    int qrow = (w*16 + l15)*72;
    qh[0] = *(const f16x8*)&Qh[qrow + quad*8];
    qh[1] = *(const f16x8*)&Qh[qrow + 32 + quad*8];
    ql[0] = *(const f16x8*)&Ql[qrow + quad*8];
    ql[1] = *(const f16x8*)&Ql[qrow + 32 + quad*8];
  }

  f32x4 S[16];
  #pragma unroll
  for (int t = 0; t < 16; t++) S[t] = (f32x4){0.f,0.f,0.f,0.f};

  // ---- QK^T over 4 chunks of 64 keys ----
  for (int c = 0; c < 4; c++) {
    if (c) __syncthreads();
    #pragma unroll
    for (int i = 0; i < 4; i++) {
      int idx = tid + 256*i;
      int row = idx >> 4, c4 = idx & 15;
      float4 v = *(const float4*)&Kf[(size_t)(key0 + c*64 + row)*128 + g*64 + c4*4];
      f16x4 hv, lv;
      hv.x = (_Float16)v.x; lv.x = (_Float16)(v.x - (float)hv.x);
      hv.y = (_Float16)v.y; lv.y = (_Float16)(v.y - (float)hv.y);
      hv.z = (_Float16)v.z; lv.z = (_Float16)(v.z - (float)hv.z);
      hv.w = (_Float16)v.w; lv.w = (_Float16)(v.w - (float)hv.w);
      *(f16x4*)&Kh[row*72 + c4*4] = hv;
      *(f16x4*)&Kl[row*72 + c4*4] = lv;
    }
    __syncthreads();
    #pragma unroll
    for (int t = 0; t < 4; t++) {
      int krow = (t*16 + l15)*72;
      f16x8 kh0 = *(const f16x8*)&Kh[krow + quad*8];
      f16x8 kh1 = *(const f16x8*)&Kh[krow + 32 + quad*8];
      f16x8 kl0 = *(const f16x8*)&Kl[krow + quad*8];
      f16x8 kl1 = *(const f16x8*)&Kl[krow + 32 + quad*8];
      int ti = c*4 + t;
      S[ti] = __builtin_amdgcn_mfma_f32_16x16x32_f16(qh[0], kh0, S[ti], 0, 0, 0);
      S[ti] = __builtin_amdgcn_mfma_f32_16x16x32_f16(ql[0], kh0, S[ti], 0, 0, 0);
      S[ti] = __builtin_amdgcn_mfma_f32_16x16x32_f16(qh[0], kl0, S[ti], 0, 0, 0);
      S[ti] = __builtin_amdgcn_mfma_f32_16x16x32_f16(qh[1], kh1, S[ti], 0, 0, 0);
      S[ti] = __builtin_amdgcn_mfma_f32_16x16x32_f16(ql[1], kh1, S[ti], 0, 0, 0);
      S[ti] = __builtin_amdgcn_mfma_f32_16x16x32_f16(qh[1], kl1, S[ti], 0, 0, 0);
    }
  }

  // ---- softmax (scores = S * 0.125), in-register ----
  float lrow[4];
  #pragma unroll
  for (int r = 0; r < 4; r++) {
    float mx = S[0][r];
    #pragma unroll
    for (int t = 1; t < 16; t++) mx = fmaxf(mx, S[t][r]);
    mx = fmaxf(mx, __shfl_xor(mx, 1)); mx = fmaxf(mx, __shfl_xor(mx, 2));
    mx = fmaxf(mx, __shfl_xor(mx, 4)); mx = fmaxf(mx, __shfl_xor(mx, 8));
    float sum = 0.f;
    #pragma unroll
    for (int t = 0; t < 16; t++) {
      float e = __expf((S[t][r] - mx) * 0.125f);
      S[t][r] = e; sum += e;
    }
    sum += __shfl_xor(sum, 1); sum += __shfl_xor(sum, 2);
    sum += __shfl_xor(sum, 4); sum += __shfl_xor(sum, 8);
    lrow[r] = sum;
  }
  if (l15 == 0) {
    #pragma unroll
    for (int r = 0; r < 4; r++) linv[w*16 + quad*4 + r] = 1.f / lrow[r];
  }
  __syncthreads();   // all K/Q LDS reads done -> safe to overwrite with P

  // ---- P (f16) to LDS, paired b32 writes ----
  #pragma unroll
  for (int r = 0; r < 4; r++) {
    int q = w*16 + quad*4 + r;
    bool mine = (l15 & 1) ? (r >= 2) : (r < 2);
    #pragma unroll
    for (int t = 0; t < 16; t++) {
      float own = S[t][r];
      float oth = __shfl_xor(own, 1);
      if (mine) {
        float e0 = (l15 & 1) ? oth : own;
        float e1 = (l15 & 1) ? own : oth;
        *(unsigned*)&Pm[q*264 + t*16 + (l15 & ~1)] = pk2(e0, e1);
      }
    }
  }
  __syncthreads();

  // ---- PV ----
  f32x4 O[4];
  #pragma unroll
  for (int t = 0; t < 4; t++) O[t] = (f32x4){0.f,0.f,0.f,0.f};
  {
    int prow = (w*16 + l15)*264;
    #pragma unroll
    for (int ks = 0; ks < 8; ks++) {
      f16x8 pa = *(const f16x8*)&Pm[prow + ks*32 + quad*8];
      #pragma unroll
      for (int t = 0; t < 4; t++) {
        f16x8 vb = *(const f16x8*)&Vt[(t*16 + l15)*264 + ks*32 + quad*8];
        O[t] = __builtin_amdgcn_mfma_f32_16x16x32_f16(pa, vb, O[t], 0, 0, 0);
      }
    }
  }

  // ---- epilogue ----
  #pragma unroll
  for (int r = 0; r < 4; r++) {
    int qlocal = w*16 + quad*4 + r;
    float inv = linv[qlocal];
    int orow = b*4096 + n*256 + qb*64 + qlocal;
    #pragma unroll
    for (int t = 0; t < 4; t++)
      Ao[(size_t)orow*1024 + h*64 + t*16 + l15] = O[t][r] * inv;
  }
}

// ---------------- gating (fp64 logits) ----------------
__global__ __launch_bounds__(256) void gating_kernel(
    const float* __restrict__ h, const float* __restrict__ g2, const float* __restrict__ b2,
    const float* __restrict__ Wg, const float* __restrict__ bg,
    int* __restrict__ cnt, int* __restrict__ bucket, float* __restrict__ bucketP,
    int* __restrict__ bucketS, float* __restrict__ entPartial) {
  int tid = threadIdx.x, lane = tid & 63, wid = tid >> 6;
  int tok = blockIdx.x*4 + wid;
  const float* row = h + (size_t)tok * 1024;
  float xv[16];
  #pragma unroll
  for (int q = 0; q < 4; q++) *(float4*)&xv[q*4] = ((const float4*)row)[lane*4 + q];
  double s = 0.0, s2 = 0.0;
  #pragma unroll
  for (int j = 0; j < 16; j++) { double d = (double)xv[j]; s += d; s2 += d*d; }
  s = wave_sum64d(s); s2 = wave_sum64d(s2);
  double mu = s / 1024.0;
  double var = s2 / 1024.0 - mu*mu;
  double rs = 1.0 / sqrt(var + 1e-5);
  double acc[8] = {};
  #pragma unroll
  for (int q = 0; q < 4; q++) {
    #pragma unroll
    for (int j = 0; j < 4; j++) {
      int i = lane*16 + q*4 + j;
      double xn = ((double)xv[q*4+j] - mu) * rs * (double)g2[i] + (double)b2[i];
      const float4 w0 = *(const float4*)&Wg[(size_t)i*8];
      const float4 w1 = *(const float4*)&Wg[(size_t)i*8 + 4];
      acc[0] += xn*(double)w0.x; acc[1] += xn*(double)w0.y;
      acc[2] += xn*(double)w0.z; acc[3] += xn*(double)w0.w;
      acc[4] += xn*(double)w1.x; acc[5] += xn*(double)w1.y;
      acc[6] += xn*(double)w1.z; acc[7] += xn*(double)w1.w;
    }
  }
  #pragma unroll
  for (int e = 0; e < 8; e++) {
    acc[e] = wave_sum64d(acc[e]);
    acc[e] += (double)bg[e];
  }
  double mx = acc[0];
  #pragma unroll
  for (int e = 1; e < 8; e++) mx = acc[e] > mx ? acc[e] : mx;
  double ex[8], Z = 0.0;
  #pragma unroll
  for (int e = 0; e < 8; e++) { ex[e] = exp(acc[e] - mx); Z += ex[e]; }
  double invZ = 1.0 / Z;
  double ent = 0.0;
  double p[8];
  #pragma unroll
  for (int e = 0; e < 8; e++) { p[e] = ex[e]*invZ; ent -= p[e]*log(p[e] + 1e-8); }
  int e1 = 0;
  #pragma unroll
  for (int e = 1; e < 8; e++) if (acc[e] > acc[e1]) e1 = e;
  int e2 = (e1 == 0) ? 1 : 0;
  #pragma unroll
  for (int e = 0; e < 8; e++) if (e != e1 && acc[e] > acc[e2]) e2 = e;
  if (lane == 0) {
    int i1 = atomicAdd(&cnt[e1], 1);
    bucket[e1*8192 + i1] = tok; bucketP[e1*8192 + i1] = (float)p[e1]; bucketS[e1*8192 + i1] = 0;
    int i2 = atomicAdd(&cnt[e2], 1);
    bucket[e2*8192 + i2] = tok; bucketP[e2*8192 + i2] = (float)p[e2]; bucketS[e2*8192 + i2] = 1;
  }
  __shared__ float eb[4];
  if (lane == 0) eb[wid] = (float)ent;
  __syncthreads();
  if (tid == 0) entPartial[blockIdx.x] = eb[0]+eb[1]+eb[2]+eb[3];
}

__global__ __launch_bounds__(256) void aux_kernel(const float* __restrict__ entPartial,
    const int* __restrict__ cnt, float* __restrict__ auxOut) {
  int tid = threadIdx.x;
  float s = 0.f;
  for (int i = tid; i < 2048; i += 256) s += entPartial[i];
  s = wave_sum64(s);
  __shared__ float pa[4];
  if ((tid & 63) == 0) pa[tid >> 6] = s;
  __syncthreads();
  if (tid == 0) {
    float tot = pa[0]+pa[1]+pa[2]+pa[3];
    float entMean = tot / 8192.f;
    float pen = 0.f;
    for (int e = 0; e < 8; e++) {
      float usage = (float)cnt[e] / (8192.f + 1e-8f);
      pen += fmaxf(usage - 0.4f, 0.f);
    }
    auxOut[0] = 0.05f * entMean + pen;
  }
}

// ---------------- We transpose (fp32 -> bf16, per expert) ----------------
__global__ void transpose_We(const float* __restrict__ We, short* __restrict__ WeT) {
  int e = blockIdx.z;
  __shared__ float tile[32][33];
  int kt = blockIdx.x, nt = blockIdx.y;
  int tx = threadIdx.x, ty = threadIdx.y;
  const float* src = We + (size_t)e * 1048576;
  short* dst = WeT + (size_t)e * 1048576;
  #pragma unroll
  for (int i = 0; i < 4; i++)
    tile[ty + 8*i][tx] = src[(size_t)(kt*32 + ty + 8*i)*1024 + nt*32 + tx];
  __syncthreads();
  #pragma unroll
  for (int i = 0; i < 4; i++)
    dst[(size_t)(nt*32 + ty + 8*i)*1024 + kt*32 + tx] = f2bf(tile[tx][ty + 8*i]);
}

// ---------------- bf16 MFMA grouped MoE GEMM ----------------
__global__ __launch_bounds__(256) void moe_gemm(
    const short* __restrict__ hln, const short* __restrict__ WeT,
    const float* __restrict__ be, const int* __restrict__ cnt,
    const int* __restrict__ bucket, const float* __restrict__ bucketP,
    const int* __restrict__ bucketS,
    float* __restrict__ slot0, float* __restrict__ slot1) {
  int e = blockIdx.z;
  int count = cnt[e];
  int mtile = blockIdx.x;
  if (mtile * 128 >= count) return;
  int n0 = blockIdx.y * 128;
  __shared__ short As[128*72];
  __shared__ short Bs[128*72];
  __shared__ int   toks[128];
  __shared__ float pws[128];
  __shared__ int   sls[128];
  int tid = threadIdx.x;
  if (tid < 128) {
    int idx = mtile*128 + tid;
    int ic = idx < count ? idx : count - 1;
    toks[tid] = bucket[e*8192 + ic];
    pws[tid]  = bucketP[e*8192 + ic];
    sls[tid]  = bucketS[e*8192 + ic];
  }
  __syncthreads();
  int mytok[4];
  #pragma unroll
  for (int i = 0; i < 4; i++) mytok[i] = toks[(tid + 256*i) >> 3];
  const short* Bt = WeT + (size_t)e * 1048576;
  int lane = tid & 63, wid = tid >> 6;
  int wm = (wid & 1) * 64, wn = (wid >> 1) * 64;
  int l15 = lane & 15, quad = lane >> 4;
  f32x4 acc[4][4] = {};
  for (int kb = 0; kb < 1024; kb += 64) {
    __syncthreads();
    #pragma unroll
    for (int i = 0; i < 4; i++) {
      int c = tid + 256*i;
      int row = c >> 3, cb = c & 7;
      *(uint4*)&As[row*72 + cb*8] = *(const uint4*)&hln[(size_t)mytok[i]*1024 + kb + cb*8];
      *(uint4*)&Bs[row*72 + cb*8] = *(const uint4*)&Bt[(size_t)(n0+row)*1024 + kb + cb*8];
    }
    __syncthreads();
    #pragma unroll
    for (int ks = 0; ks < 2; ks++) {
      bf16x8 af[4], bfr[4];
      #pragma unroll
      for (int mt = 0; mt < 4; mt++)
        af[mt] = *(const bf16x8*)&As[(wm + mt*16 + l15)*72 + ks*32 + quad*8];
      #pragma unroll
      for (int nt = 0; nt < 4; nt++)
        bfr[nt] = *(const bf16x8*)&Bs[(wn + nt*16 + l15)*72 + ks*32 + quad*8];
      #pragma unroll
      for (int mt = 0; mt < 4; mt++)
        #pragma unroll
        for (int nt = 0; nt < 4; nt++)
          acc[mt][nt] = __builtin_amdgcn_mfma_f32_16x16x32_bf16(af[mt], bfr[nt], acc[mt][nt], 0, 0, 0);
    }
  }
  #pragma unroll
  for (int mt = 0; mt < 4; mt++) {
    #pragma unroll
    for (int r = 0; r < 4; r++) {
      int m = wm + mt*16 + quad*4 + r;
      if (mtile*128 + m < count) {
        int tok = toks[m];
        float pp = pws[m];
        float* dst = sls[m] ? slot1 : slot0;
        #pragma unroll
        for (int nt = 0; nt < 4; nt++) {
          int col = n0 + wn + nt*16 + l15;
          dst[(size_t)tok*1024 + col] = pp * (acc[mt][nt][r] + be[e*1024 + col]);
        }
      }
    }
  }
}

// ---------------- final combine ----------------
__global__ __launch_bounds__(256) void final_add(float* __restrict__ out,
    const float* __restrict__ s0, const float* __restrict__ s1) {
  const int total = 8388608 / 4;
  for (int i = blockIdx.x*256 + threadIdx.x; i < total; i += gridDim.x*256) {
    float4 a = ((float4*)out)[i];
    const float4 x0 = ((const float4*)s0)[i];
    const float4 x1 = ((const float4*)s1)[i];
    a.x += x0.x + x1.x; a.y += x0.y + x1.y; a.z += x0.z + x1.z; a.w += x0.w + x1.w;
    ((float4*)out)[i] = a;
  }
}

// ---------------- host launcher ----------------
extern "C" void kernel_launch(void* const* d_in, const int* in_sizes, int n_in,
                              void* d_out, int out_size, void* d_ws, size_t ws_size,
                              hipStream_t stream) {
  const float* x    = (const float*)d_in[0];
  const float* Wq   = (const float*)d_in[1];
  const float* bq   = (const float*)d_in[2];
  const float* Wk   = (const float*)d_in[3];
  const float* bk   = (const float*)d_in[4];
  const float* Wv   = (const float*)d_in[5];
  const float* bv   = (const float*)d_in[6];
  const float* Wo   = (const float*)d_in[7];
  const float* bo   = (const float*)d_in[8];
  const float* ln1g = (const float*)d_in[9];
  const float* ln1b = (const float*)d_in[10];
  const float* ln2g = (const float*)d_in[11];
  const float* ln2b = (const float*)d_in[12];
  const float* Wg   = (const float*)d_in[13];
  const float* bg   = (const float*)d_in[14];
  const float* We   = (const float*)d_in[15];
  const float* be   = (const float*)d_in[16];
  float* out = (float*)d_out;

  char* ws = (char*)d_ws;
  size_t off = 0;
  auto alloc = [&](size_t bytes) { char* p = ws + off; off += (bytes + 255) & ~(size_t)255; return p; };
  float* xln   = (float*)alloc(33554432);   // 8192x1024 f32; reused as attn_out
  float* Qs    = (float*)alloc(33554432);   // 8192x1024 f32 (UNscaled Q); reused as hln
  float* Kf    = (float*)alloc(4194304);    // 8192x128 f32
  float* Vf    = (float*)alloc(4194304);    // 8192x128 f32
  short* WeT   = (short*)alloc(16777216);   // 8x1024x1024 bf16
  float* slot0 = (float*)alloc(33554432);
  float* slot1 = (float*)alloc(33554432);
  int*   bucket  = (int*)alloc(262144);
  float* bucketP = (float*)alloc(262144);
  int*   bucketS = (int*)alloc(262144);
  int*   cnt     = (int*)alloc(256);
  float* entPartial = (float*)alloc(8192);
  float* attn_out = xln;        // alias: xln dead after QKV GEMM
  short* hln      = (short*)Qs; // alias: Qs dead after attention
  _Float16* WoTh    = (_Float16*)slot0;
  _Float16* WoTl    = (_Float16*)(slot0 + 524288);
  _Float16* BTqkv_h = (_Float16*)slot1;
  _Float16* BTqkv_l = (_Float16*)((char*)slot1 + 2621440);

  hipMemsetAsync(cnt, 0, 256, stream);
  t_w_f16<<<dim3(32, 32), dim3(32, 8), 0, stream>>>(Wq, 1024, BTqkv_h, BTqkv_l, 0);
  t_w_f16<<<dim3(32, 4),  dim3(32, 8), 0, stream>>>(Wk, 128,  BTqkv_h, BTqkv_l, 1024);
  t_w_f16<<<dim3(32, 4),  dim3(32, 8), 0, stream>>>(Wv, 128,  BTqkv_h, BTqkv_l, 1152);
  t_w_f16<<<dim3(32, 32), dim3(32, 8), 0, stream>>>(Wo, 1024, WoTh, WoTl, 0);
  transpose_We<<<dim3(32,32,8), dim3(32,8), 0, stream>>>(We, WeT);

  ln_f32<<<8192, 256, 0, stream>>>(x, ln1g, ln1b, xln);
  gemm_f16x2<0><<<dim3(64,10), 256, 0, stream>>>(xln, BTqkv_h, BTqkv_l, bq, bk, bv,
                                                 nullptr, Qs, Kf, Vf);
  attn_mfma<<<dim3(4,16,32), 256, 0, stream>>>(Qs, Kf, Vf, attn_out);
  gemm_f16x2<1><<<dim3(64,8), 256, 0, stream>>>(attn_out, WoTh, WoTl, bo, nullptr, nullptr,
                                                x, out, nullptr, nullptr);
  ln_bf16<<<8192, 256, 0, stream>>>(out, ln2g, ln2b, hln);
  gating_kernel<<<2048, 256, 0, stream>>>(out, ln2g, ln2b, Wg, bg,
                                          cnt, bucket, bucketP, bucketS, entPartial);
  aux_kernel<<<1, 256, 0, stream>>>(entPartial, cnt, out + 8388608);
  moe_gemm<<<dim3(64,8,8), 256, 0, stream>>>(hln, WeT, be, cnt, bucket, bucketP, bucketS, slot0, slot1);
  final_add<<<2048, 256, 0, stream>>>(out, slot0, slot1);
}

// Round 4
// 618.624 us; speedup vs baseline: 2.0194x; 1.2748x over previous
//
#include <hip/hip_runtime.h>
#include <hip/hip_bf16.h>
#include <stdint.h>

// ---------------- types / helpers ----------------
typedef __attribute__((ext_vector_type(8))) short bf16x8;
typedef __attribute__((ext_vector_type(8))) _Float16 f16x8;
typedef __attribute__((ext_vector_type(4))) _Float16 f16x4;
typedef __attribute__((ext_vector_type(4))) float f32x4;

__device__ __forceinline__ short f2bf(float f) {
  __hip_bfloat16 h = __float2bfloat16(f);
  union { __hip_bfloat16 h; short s; } u; u.h = h; return u.s;
}

__device__ __forceinline__ unsigned pk2(float a, float b) {
  union { _Float16 h; unsigned short s; } ua, ub;
  ua.h = (_Float16)a; ub.h = (_Float16)b;
  return (unsigned)ua.s | ((unsigned)ub.s << 16);
}

__device__ __forceinline__ float wave_sum64(float v) {
  #pragma unroll
  for (int off = 1; off < 64; off <<= 1) v += __shfl_xor(v, off);
  return v;
}
__device__ __forceinline__ double wave_sum64d(double v) {
  #pragma unroll
  for (int off = 1; off < 64; off <<= 1) v += __shfl_xor(v, off);
  return v;
}

// ---------------- LN kernels ----------------
__global__ __launch_bounds__(256) void ln_f32(const float* __restrict__ x,
    const float* __restrict__ g, const float* __restrict__ b, float* __restrict__ out) {
  int t = blockIdx.x, tid = threadIdx.x;
  const float4 v = ((const float4*)(x + (size_t)t * 1024))[tid];
  float s = v.x + v.y + v.z + v.w;
  float s2 = v.x*v.x + v.y*v.y + v.z*v.z + v.w*v.w;
  s = wave_sum64(s); s2 = wave_sum64(s2);
  __shared__ float pa[4], pb[4];
  int wid = tid >> 6, lane = tid & 63;
  if (lane == 0) { pa[wid] = s; pb[wid] = s2; }
  __syncthreads();
  float S = pa[0]+pa[1]+pa[2]+pa[3], S2 = pb[0]+pb[1]+pb[2]+pb[3];
  float mu = S * (1.f/1024.f);
  float var = S2 * (1.f/1024.f) - mu*mu;
  float rs = rsqrtf(var + 1e-5f);
  const float4 gv = ((const float4*)g)[tid];
  const float4 bv = ((const float4*)b)[tid];
  float4 o;
  o.x = (v.x-mu)*rs*gv.x + bv.x; o.y = (v.y-mu)*rs*gv.y + bv.y;
  o.z = (v.z-mu)*rs*gv.z + bv.z; o.w = (v.w-mu)*rs*gv.w + bv.w;
  ((float4*)(out + (size_t)t * 1024))[tid] = o;
}

// also emits per-token (mu, rs) for the gating kernel
__global__ __launch_bounds__(256) void ln_bf16(const float* __restrict__ x,
    const float* __restrict__ g, const float* __restrict__ b, short* __restrict__ out,
    float2* __restrict__ murs) {
  int t = blockIdx.x, tid = threadIdx.x;
  const float4 v = ((const float4*)(x + (size_t)t * 1024))[tid];
  float s = v.x + v.y + v.z + v.w;
  float s2 = v.x*v.x + v.y*v.y + v.z*v.z + v.w*v.w;
  s = wave_sum64(s); s2 = wave_sum64(s2);
  __shared__ float pa[4], pb[4];
  int wid = tid >> 6, lane = tid & 63;
  if (lane == 0) { pa[wid] = s; pb[wid] = s2; }
  __syncthreads();
  float S = pa[0]+pa[1]+pa[2]+pa[3], S2 = pb[0]+pb[1]+pb[2]+pb[3];
  float mu = S * (1.f/1024.f);
  float var = S2 * (1.f/1024.f) - mu*mu;
  float rs = rsqrtf(var + 1e-5f);
  if (tid == 0) murs[t] = make_float2(mu, rs);
  const float4 gv = ((const float4*)g)[tid];
  const float4 bv = ((const float4*)b)[tid];
  short4 o;
  o.x = f2bf((v.x-mu)*rs*gv.x + bv.x); o.y = f2bf((v.y-mu)*rs*gv.y + bv.y);
  o.z = f2bf((v.z-mu)*rs*gv.z + bv.z); o.w = f2bf((v.w-mu)*rs*gv.w + bv.w);
  ((short4*)(out + (size_t)t * 1024))[tid] = o;
}

// ---------------- weight transpose + fp16 hi/lo split ----------------
__global__ void t_w_f16(const float* __restrict__ src, int srcN,
                        _Float16* __restrict__ dh, _Float16* __restrict__ dl, int dstRow0) {
  __shared__ float tile[32][33];
  int kt = blockIdx.x, nt = blockIdx.y;
  int tx = threadIdx.x, ty = threadIdx.y;
  #pragma unroll
  for (int i = 0; i < 4; i++)
    tile[ty + 8*i][tx] = src[(size_t)(kt*32 + ty + 8*i)*srcN + nt*32 + tx];
  __syncthreads();
  #pragma unroll
  for (int i = 0; i < 4; i++) {
    float v = tile[tx][ty + 8*i];
    _Float16 h = (_Float16)v;
    _Float16 l = (_Float16)((v - (float)h) * 2048.0f);
    size_t o = (size_t)(dstRow0 + nt*32 + ty + 8*i)*1024 + kt*32 + tx;
    dh[o] = h; dl[o] = l;
  }
}

// ---------------- split-fp16 MFMA GEMM ----------------
template<int MODE>
__global__ __launch_bounds__(256) void gemm_f16x2(
    const float* __restrict__ A,
    const _Float16* __restrict__ BTh, const _Float16* __restrict__ BTl,
    const float* __restrict__ b0, const float* __restrict__ b1, const float* __restrict__ b2,
    const float* __restrict__ resid,
    float* __restrict__ out0, float* __restrict__ out1, float* __restrict__ out2) {
  int m0 = blockIdx.x * 128;
  int y = blockIdx.y;
  int n0 = y * 128;
  float* dst; const float* biasp; int dcol0, ld;
  if (MODE == 0) {
    if (y < 8)      { dst = out0; biasp = b0 + y*128; dcol0 = y*128; ld = 1024; }
    else if (y == 8){ dst = out1; biasp = b1; dcol0 = 0; ld = 128; }
    else            { dst = out2; biasp = b2; dcol0 = 0; ld = 128; }
  } else            { dst = out0; biasp = b0 + y*128; dcol0 = y*128; ld = 1024; }

  __shared__ _Float16 Ah[128*72];
  __shared__ _Float16 Al[128*72];
  __shared__ _Float16 Bh[128*72];
  __shared__ _Float16 Bl[128*72];
  int tid = threadIdx.x;
  int lane = tid & 63, wid = tid >> 6;
  int wm = (wid & 1) * 64, wn = (wid >> 1) * 64;
  int l15 = lane & 15, quad = lane >> 4;
  f32x4 accM[4][4] = {};
  f32x4 accC[4][4] = {};
  for (int kb = 0; kb < 1024; kb += 64) {
    __syncthreads();
    #pragma unroll
    for (int i = 0; i < 8; i++) {
      int idx = tid + 256*i;
      int row = idx >> 4, c4 = idx & 15;
      float4 v = *(const float4*)&A[(size_t)(m0+row)*1024 + kb + c4*4];
      f16x4 hv, lv;
      hv.x = (_Float16)v.x; lv.x = (_Float16)((v.x - (float)hv.x) * 2048.f);
      hv.y = (_Float16)v.y; lv.y = (_Float16)((v.y - (float)hv.y) * 2048.f);
      hv.z = (_Float16)v.z; lv.z = (_Float16)((v.z - (float)hv.z) * 2048.f);
      hv.w = (_Float16)v.w; lv.w = (_Float16)((v.w - (float)hv.w) * 2048.f);
      *(f16x4*)&Ah[row*72 + c4*4] = hv;
      *(f16x4*)&Al[row*72 + c4*4] = lv;
    }
    #pragma unroll
    for (int i = 0; i < 4; i++) {
      int idx = tid + 256*i;
      int row = idx >> 3, c8 = idx & 7;
      *(uint4*)&Bh[row*72 + c8*8] = *(const uint4*)&BTh[(size_t)(n0+row)*1024 + kb + c8*8];
      *(uint4*)&Bl[row*72 + c8*8] = *(const uint4*)&BTl[(size_t)(n0+row)*1024 + kb + c8*8];
    }
    __syncthreads();
    #pragma unroll
    for (int ks = 0; ks < 2; ks++) {
      f16x8 ah[4], al[4], bh[4], bl[4];
      #pragma unroll
      for (int mt = 0; mt < 4; mt++) {
        ah[mt] = *(const f16x8*)&Ah[(wm + mt*16 + l15)*72 + ks*32 + quad*8];
        al[mt] = *(const f16x8*)&Al[(wm + mt*16 + l15)*72 + ks*32 + quad*8];
      }
      #pragma unroll
      for (int nt = 0; nt < 4; nt++) {
        bh[nt] = *(const f16x8*)&Bh[(wn + nt*16 + l15)*72 + ks*32 + quad*8];
        bl[nt] = *(const f16x8*)&Bl[(wn + nt*16 + l15)*72 + ks*32 + quad*8];
      }
      #pragma unroll
      for (int mt = 0; mt < 4; mt++)
        #pragma unroll
        for (int nt = 0; nt < 4; nt++) {
          accM[mt][nt] = __builtin_amdgcn_mfma_f32_16x16x32_f16(ah[mt], bh[nt], accM[mt][nt], 0, 0, 0);
          accC[mt][nt] = __builtin_amdgcn_mfma_f32_16x16x32_f16(ah[mt], bl[nt], accC[mt][nt], 0, 0, 0);
          accC[mt][nt] = __builtin_amdgcn_mfma_f32_16x16x32_f16(al[mt], bh[nt], accC[mt][nt], 0, 0, 0);
        }
    }
  }
  const float inv2048 = 1.0f / 2048.0f;
  #pragma unroll
  for (int mt = 0; mt < 4; mt++)
    #pragma unroll
    for (int r = 0; r < 4; r++) {
      int row = m0 + wm + mt*16 + quad*4 + r;
      #pragma unroll
      for (int nt = 0; nt < 4; nt++) {
        int c = wn + nt*16 + l15;
        float v = accM[mt][nt][r] + accC[mt][nt][r]*inv2048 + biasp[c];
        if (MODE == 1) v += resid[(size_t)row*1024 + dcol0 + c];
        dst[(size_t)row*ld + dcol0 + c] = v;
      }
    }
}

// ---------------- MFMA windowed attention ----------------
__global__ __launch_bounds__(256, 2) void attn_mfma(
    const float* __restrict__ Qs, const float* __restrict__ Kf, const float* __restrict__ Vf,
    float* __restrict__ Ao) {
  int qb = blockIdx.x, n = blockIdx.y;
  int b = blockIdx.z >> 4, h = blockIdx.z & 15;
  int g = h & 1;
  int tid = threadIdx.x;
  int lane = tid & 63, w = tid >> 6;
  int l15 = lane & 15, quad = lane >> 4;

  __shared__ __align__(16) char smem[70912];
  _Float16* Vt = (_Float16*)smem;                 // [64][264]
  _Float16* Qh = (_Float16*)(smem + 33792);       // [64][72]
  _Float16* Ql = (_Float16*)(smem + 43008);
  _Float16* Kh = (_Float16*)(smem + 52224);
  _Float16* Kl = (_Float16*)(smem + 61440);
  _Float16* Pm = (_Float16*)(smem + 33792);       // alias over Q/K
  float*   linv = (float*)(smem + 70656);

  int qtok0 = b*4096 + n*128 + qb*64;
  int key0  = b*4096 + n*128;

  #pragma unroll
  for (int i = 0; i < 4; i++) {
    int idx = tid + 256*i;
    int row = idx >> 4, c4 = idx & 15;
    float4 v = *(const float4*)&Qs[(size_t)(qtok0+row)*1024 + h*64 + c4*4];
    f16x4 hv, lv;
    hv.x = (_Float16)v.x; lv.x = (_Float16)(v.x - (float)hv.x);
    hv.y = (_Float16)v.y; lv.y = (_Float16)(v.y - (float)hv.y);
    hv.z = (_Float16)v.z; lv.z = (_Float16)(v.z - (float)hv.z);
    hv.w = (_Float16)v.w; lv.w = (_Float16)(v.w - (float)hv.w);
    *(f16x4*)&Qh[row*72 + c4*4] = hv;
    *(f16x4*)&Ql[row*72 + c4*4] = lv;
  }
  {
    int kk = tid >> 4, dd = tid & 15;
    #pragma unroll
    for (int i = 0; i < 8; i++) {
      int p = i*16 + kk;
      float4 v0 = *(const float4*)&Vf[(size_t)(key0 + 2*p    )*128 + g*64 + dd*4];
      float4 v1 = *(const float4*)&Vf[(size_t)(key0 + 2*p + 1)*128 + g*64 + dd*4];
      *(unsigned*)&Vt[(dd*4+0)*264 + 2*p] = pk2(v0.x, v1.x);
      *(unsigned*)&Vt[(dd*4+1)*264 + 2*p] = pk2(v0.y, v1.y);
      *(unsigned*)&Vt[(dd*4+2)*264 + 2*p] = pk2(v0.z, v1.z);
      *(unsigned*)&Vt[(dd*4+3)*264 + 2*p] = pk2(v0.w, v1.w);
    }
  }
  __syncthreads();

  f16x8 qh[2], ql[2];
  {
    int qrow = (w*16 + l15)*72;
    qh[0] = *(const f16x8*)&Qh[qrow + quad*8];
    qh[1] = *(const f16x8*)&Qh[qrow + 32 + quad*8];
    ql[0] = *(const f16x8*)&Ql[qrow + quad*8];
    ql[1] = *(const f16x8*)&Ql[qrow + 32 + quad*8];
  }

  f32x4 S[16];
  #pragma unroll
  for (int t = 0; t < 16; t++) S[t] = (f32x4){0.f,0.f,0.f,0.f};

  for (int c = 0; c < 4; c++) {
    if (c) __syncthreads();
    #pragma unroll
    for (int i = 0; i < 4; i++) {
      int idx = tid + 256*i;
      int row = idx >> 4, c4 = idx & 15;
      float4 v = *(const float4*)&Kf[(size_t)(key0 + c*64 + row)*128 + g*64 + c4*4];
      f16x4 hv, lv;
      hv.x = (_Float16)v.x; lv.x = (_Float16)(v.x - (float)hv.x);
      hv.y = (_Float16)v.y; lv.y = (_Float16)(v.y - (float)hv.y);
      hv.z = (_Float16)v.z; lv.z = (_Float16)(v.z - (float)hv.z);
      hv.w = (_Float16)v.w; lv.w = (_Float16)(v.w - (float)hv.w);
      *(f16x4*)&Kh[row*72 + c4*4] = hv;
      *(f16x4*)&Kl[row*72 + c4*4] = lv;
    }
    __syncthreads();
    #pragma unroll
    for (int t = 0; t < 4; t++) {
      int krow = (t*16 + l15)*72;
      f16x8 kh0 = *(const f16x8*)&Kh[krow + quad*8];
      f16x8 kh1 = *(const f16x8*)&Kh[krow + 32 + quad*8];
      f16x8 kl0 = *(const f16x8*)&Kl[krow + quad*8];
      f16x8 kl1 = *(const f16x8*)&Kl[krow + 32 + quad*8];
      int ti = c*4 + t;
      S[ti] = __builtin_amdgcn_mfma_f32_16x16x32_f16(qh[0], kh0, S[ti], 0, 0, 0);
      S[ti] = __builtin_amdgcn_mfma_f32_16x16x32_f16(ql[0], kh0, S[ti], 0, 0, 0);
      S[ti] = __builtin_amdgcn_mfma_f32_16x16x32_f16(qh[0], kl0, S[ti], 0, 0, 0);
      S[ti] = __builtin_amdgcn_mfma_f32_16x16x32_f16(qh[1], kh1, S[ti], 0, 0, 0);
      S[ti] = __builtin_amdgcn_mfma_f32_16x16x32_f16(ql[1], kh1, S[ti], 0, 0, 0);
      S[ti] = __builtin_amdgcn_mfma_f32_16x16x32_f16(qh[1], kl1, S[ti], 0, 0, 0);
    }
  }

  float lrow[4];
  #pragma unroll
  for (int r = 0; r < 4; r++) {
    float mx = S[0][r];
    #pragma unroll
    for (int t = 1; t < 16; t++) mx = fmaxf(mx, S[t][r]);
    mx = fmaxf(mx, __shfl_xor(mx, 1)); mx = fmaxf(mx, __shfl_xor(mx, 2));
    mx = fmaxf(mx, __shfl_xor(mx, 4)); mx = fmaxf(mx, __shfl_xor(mx, 8));
    float sum = 0.f;
    #pragma unroll
    for (int t = 0; t < 16; t++) {
      float e = __expf((S[t][r] - mx) * 0.125f);
      S[t][r] = e; sum += e;
    }
    sum += __shfl_xor(sum, 1); sum += __shfl_xor(sum, 2);
    sum += __shfl_xor(sum, 4); sum += __shfl_xor(sum, 8);
    lrow[r] = sum;
  }
  if (l15 == 0) {
    #pragma unroll
    for (int r = 0; r < 4; r++) linv[w*16 + quad*4 + r] = 1.f / lrow[r];
  }
  __syncthreads();

  #pragma unroll
  for (int r = 0; r < 4; r++) {
    int q = w*16 + quad*4 + r;
    bool mine = (l15 & 1) ? (r >= 2) : (r < 2);
    #pragma unroll
    for (int t = 0; t < 16; t++) {
      float own = S[t][r];
      float oth = __shfl_xor(own, 1);
      if (mine) {
        float e0 = (l15 & 1) ? oth : own;
        float e1 = (l15 & 1) ? own : oth;
        *(unsigned*)&Pm[q*264 + t*16 + (l15 & ~1)] = pk2(e0, e1);
      }
    }
  }
  __syncthreads();

  f32x4 O[4];
  #pragma unroll
  for (int t = 0; t < 4; t++) O[t] = (f32x4){0.f,0.f,0.f,0.f};
  {
    int prow = (w*16 + l15)*264;
    #pragma unroll
    for (int ks = 0; ks < 8; ks++) {
      f16x8 pa = *(const f16x8*)&Pm[prow + ks*32 + quad*8];
      #pragma unroll
      for (int t = 0; t < 4; t++) {
        f16x8 vb = *(const f16x8*)&Vt[(t*16 + l15)*264 + ks*32 + quad*8];
        O[t] = __builtin_amdgcn_mfma_f32_16x16x32_f16(pa, vb, O[t], 0, 0, 0);
      }
    }
  }

  #pragma unroll
  for (int r = 0; r < 4; r++) {
    int qlocal = w*16 + quad*4 + r;
    float inv = linv[qlocal];
    int orow = b*4096 + n*256 + qb*64 + qlocal;
    #pragma unroll
    for (int t = 0; t < 4; t++)
      Ao[(size_t)orow*1024 + h*64 + t*16 + l15] = O[t][r] * inv;
  }
}

// ---------------- gating phase 1: logits + top2 + entropy (NO atomics) ----------------
__global__ __launch_bounds__(256) void gating_logits(
    const float* __restrict__ h, const float2* __restrict__ murs,
    const float* __restrict__ g2, const float* __restrict__ b2,
    const float* __restrict__ Wg, const float* __restrict__ bg,
    int* __restrict__ e1e2, float2* __restrict__ p12, float* __restrict__ entArr) {
  int tid = threadIdx.x, lane = tid & 63, wid = tid >> 6;
  int tok = blockIdx.x*4 + wid;
  const float* row = h + (size_t)tok * 1024;
  float2 mr = murs[tok];
  double mu = (double)mr.x, rs = (double)mr.y;
  double acc[8] = {};
  #pragma unroll
  for (int q = 0; q < 4; q++) {
    float4 xv = ((const float4*)row)[lane*4 + q];
    float4 gv = ((const float4*)g2)[lane*4 + q];
    float4 bv = ((const float4*)b2)[lane*4 + q];
    float xs[4] = {xv.x, xv.y, xv.z, xv.w};
    float gs[4] = {gv.x, gv.y, gv.z, gv.w};
    float bs[4] = {bv.x, bv.y, bv.z, bv.w};
    #pragma unroll
    for (int j = 0; j < 4; j++) {
      int i = lane*16 + q*4 + j;
      double xn = ((double)xs[j] - mu) * rs * (double)gs[j] + (double)bs[j];
      const float4 w0 = *(const float4*)&Wg[(size_t)i*8];
      const float4 w1 = *(const float4*)&Wg[(size_t)i*8 + 4];
      acc[0] += xn*(double)w0.x; acc[1] += xn*(double)w0.y;
      acc[2] += xn*(double)w0.z; acc[3] += xn*(double)w0.w;
      acc[4] += xn*(double)w1.x; acc[5] += xn*(double)w1.y;
      acc[6] += xn*(double)w1.z; acc[7] += xn*(double)w1.w;
    }
  }
  #pragma unroll
  for (int e = 0; e < 8; e++) acc[e] = wave_sum64d(acc[e]) + (double)bg[e];
  // top2 on fp64 logits (ranking precision)
  int e1 = 0;
  #pragma unroll
  for (int e = 1; e < 8; e++) if (acc[e] > acc[e1]) e1 = e;
  int e2 = (e1 == 0) ? 1 : 0;
  #pragma unroll
  for (int e = 0; e < 8; e++) if (e != e1 && acc[e] > acc[e2]) e2 = e;
  // softmax / entropy in fp32
  float lf[8];
  #pragma unroll
  for (int e = 0; e < 8; e++) lf[e] = (float)acc[e];
  float mx = lf[0];
  #pragma unroll
  for (int e = 1; e < 8; e++) mx = fmaxf(mx, lf[e]);
  float ex[8], Z = 0.f;
  #pragma unroll
  for (int e = 0; e < 8; e++) { ex[e] = __expf(lf[e] - mx); Z += ex[e]; }
  float invZ = 1.f / Z, ent = 0.f;
  float p[8];
  #pragma unroll
  for (int e = 0; e < 8; e++) { p[e] = ex[e]*invZ; ent -= p[e]*__logf(p[e] + 1e-8f); }
  if (lane == 0) {
    e1e2[tok] = e1 | (e2 << 8);
    p12[tok]  = make_float2(p[e1], p[e2]);
    entArr[tok] = ent;
  }
}

// ---------------- gating phase 2: LDS-aggregated scatter (512 global atomics total) ----
__global__ __launch_bounds__(128) void scatter_kernel(
    const int* __restrict__ e1e2, const float2* __restrict__ p12,
    int* __restrict__ cnt, int* __restrict__ bucket, float* __restrict__ bucketP,
    int* __restrict__ bucketS) {
  __shared__ int lcnt[8], base[8];
  int tid = threadIdx.x;
  if (tid < 8) lcnt[tid] = 0;
  __syncthreads();
  int tok = blockIdx.x*128 + tid;
  int ee = e1e2[tok];
  int e1 = ee & 255, e2 = ee >> 8;
  float2 p = p12[tok];
  int o1 = atomicAdd(&lcnt[e1], 1);
  int o2 = atomicAdd(&lcnt[e2], 1);
  __syncthreads();
  if (tid < 8) base[tid] = atomicAdd(&cnt[tid], lcnt[tid]);
  __syncthreads();
  int i1 = base[e1] + o1;
  bucket[e1*8192 + i1] = tok; bucketP[e1*8192 + i1] = p.x; bucketS[e1*8192 + i1] = 0;
  int i2 = base[e2] + o2;
  bucket[e2*8192 + i2] = tok; bucketP[e2*8192 + i2] = p.y; bucketS[e2*8192 + i2] = 1;
}

__global__ __launch_bounds__(256) void aux_kernel(const float* __restrict__ entArr,
    const int* __restrict__ cnt, float* __restrict__ auxOut) {
  int tid = threadIdx.x;
  float s = 0.f;
  for (int i = tid; i < 8192; i += 256) s += entArr[i];
  s = wave_sum64(s);
  __shared__ float pa[4];
  if ((tid & 63) == 0) pa[tid >> 6] = s;
  __syncthreads();
  if (tid == 0) {
    float tot = pa[0]+pa[1]+pa[2]+pa[3];
    float entMean = tot / 8192.f;
    float pen = 0.f;
    for (int e = 0; e < 8; e++) {
      float usage = (float)cnt[e] / (8192.f + 1e-8f);
      pen += fmaxf(usage - 0.4f, 0.f);
    }
    auxOut[0] = 0.05f * entMean + pen;
  }
}

// ---------------- We transpose (fp32 -> bf16, per expert) ----------------
__global__ void transpose_We(const float* __restrict__ We, short* __restrict__ WeT) {
  int e = blockIdx.z;
  __shared__ float tile[32][33];
  int kt = blockIdx.x, nt = blockIdx.y;
  int tx = threadIdx.x, ty = threadIdx.y;
  const float* src = We + (size_t)e * 1048576;
  short* dst = WeT + (size_t)e * 1048576;
  #pragma unroll
  for (int i = 0; i < 4; i++)
    tile[ty + 8*i][tx] = src[(size_t)(kt*32 + ty + 8*i)*1024 + nt*32 + tx];
  __syncthreads();
  #pragma unroll
  for (int i = 0; i < 4; i++)
    dst[(size_t)(nt*32 + ty + 8*i)*1024 + kt*32 + tx] = f2bf(tile[tx][ty + 8*i]);
}

// ---------------- bf16 MFMA grouped MoE GEMM ----------------
__global__ __launch_bounds__(256) void moe_gemm(
    const short* __restrict__ hln, const short* __restrict__ WeT,
    const float* __restrict__ be, const int* __restrict__ cnt,
    const int* __restrict__ bucket, const float* __restrict__ bucketP,
    const int* __restrict__ bucketS,
    float* __restrict__ slot0, float* __restrict__ slot1) {
  int e = blockIdx.z;
  int count = cnt[e];
  int mtile = blockIdx.x;
  if (mtile * 128 >= count) return;
  int n0 = blockIdx.y * 128;
  __shared__ short As[128*72];
  __shared__ short Bs[128*72];
  __shared__ int   toks[128];
  __shared__ float pws[128];
  __shared__ int   sls[128];
  int tid = threadIdx.x;
  if (tid < 128) {
    int idx = mtile*128 + tid;
    int ic = idx < count ? idx : count - 1;
    toks[tid] = bucket[e*8192 + ic];
    pws[tid]  = bucketP[e*8192 + ic];
    sls[tid]  = bucketS[e*8192 + ic];
  }
  __syncthreads();
  int mytok[4];
  #pragma unroll
  for (int i = 0; i < 4; i++) mytok[i] = toks[(tid + 256*i) >> 3];
  const short* Bt = WeT + (size_t)e * 1048576;
  int lane = tid & 63, wid = tid >> 6;
  int wm = (wid & 1) * 64, wn = (wid >> 1) * 64;
  int l15 = lane & 15, quad = lane >> 4;
  f32x4 acc[4][4] = {};
  for (int kb = 0; kb < 1024; kb += 64) {
    __syncthreads();
    #pragma unroll
    for (int i = 0; i < 4; i++) {
      int c = tid + 256*i;
      int row = c >> 3, cb = c & 7;
      *(uint4*)&As[row*72 + cb*8] = *(const uint4*)&hln[(size_t)mytok[i]*1024 + kb + cb*8];
      *(uint4*)&Bs[row*72 + cb*8] = *(const uint4*)&Bt[(size_t)(n0+row)*1024 + kb + cb*8];
    }
    __syncthreads();
    #pragma unroll
    for (int ks = 0; ks < 2; ks++) {
      bf16x8 af[4], bfr[4];
      #pragma unroll
      for (int mt = 0; mt < 4; mt++)
        af[mt] = *(const bf16x8*)&As[(wm + mt*16 + l15)*72 + ks*32 + quad*8];
      #pragma unroll
      for (int nt = 0; nt < 4; nt++)
        bfr[nt] = *(const bf16x8*)&Bs[(wn + nt*16 + l15)*72 + ks*32 + quad*8];
      #pragma unroll
      for (int mt = 0; mt < 4; mt++)
        #pragma unroll
        for (int nt = 0; nt < 4; nt++)
          acc[mt][nt] = __builtin_amdgcn_mfma_f32_16x16x32_bf16(af[mt], bfr[nt], acc[mt][nt], 0, 0, 0);
    }
  }
  #pragma unroll
  for (int mt = 0; mt < 4; mt++) {
    #pragma unroll
    for (int r = 0; r < 4; r++) {
      int m = wm + mt*16 + quad*4 + r;
      if (mtile*128 + m < count) {
        int tok = toks[m];
        float pp = pws[m];
        float* dst = sls[m] ? slot1 : slot0;
        #pragma unroll
        for (int nt = 0; nt < 4; nt++) {
          int col = n0 + wn + nt*16 + l15;
          dst[(size_t)tok*1024 + col] = pp * (acc[mt][nt][r] + be[e*1024 + col]);
        }
      }
    }
  }
}

// ---------------- final combine ----------------
__global__ __launch_bounds__(256) void final_add(float* __restrict__ out,
    const float* __restrict__ s0, const float* __restrict__ s1) {
  const int total = 8388608 / 4;
  for (int i = blockIdx.x*256 + threadIdx.x; i < total; i += gridDim.x*256) {
    float4 a = ((float4*)out)[i];
    const float4 x0 = ((const float4*)s0)[i];
    const float4 x1 = ((const float4*)s1)[i];
    a.x += x0.x + x1.x; a.y += x0.y + x1.y; a.z += x0.z + x1.z; a.w += x0.w + x1.w;
    ((float4*)out)[i] = a;
  }
}

// ---------------- host launcher ----------------
extern "C" void kernel_launch(void* const* d_in, const int* in_sizes, int n_in,
                              void* d_out, int out_size, void* d_ws, size_t ws_size,
                              hipStream_t stream) {
  const float* x    = (const float*)d_in[0];
  const float* Wq   = (const float*)d_in[1];
  const float* bq   = (const float*)d_in[2];
  const float* Wk   = (const float*)d_in[3];
  const float* bk   = (const float*)d_in[4];
  const float* Wv   = (const float*)d_in[5];
  const float* bv   = (const float*)d_in[6];
  const float* Wo   = (const float*)d_in[7];
  const float* bo   = (const float*)d_in[8];
  const float* ln1g = (const float*)d_in[9];
  const float* ln1b = (const float*)d_in[10];
  const float* ln2g = (const float*)d_in[11];
  const float* ln2b = (const float*)d_in[12];
  const float* Wg   = (const float*)d_in[13];
  const float* bg   = (const float*)d_in[14];
  const float* We   = (const float*)d_in[15];
  const float* be   = (const float*)d_in[16];
  float* out = (float*)d_out;

  char* ws = (char*)d_ws;
  size_t off = 0;
  auto alloc = [&](size_t bytes) { char* p = ws + off; off += (bytes + 255) & ~(size_t)255; return p; };
  float* xln   = (float*)alloc(33554432);   // 8192x1024 f32; reused as attn_out
  float* Qs    = (float*)alloc(33554432);   // 8192x1024 f32; reused as hln
  float* Kf    = (float*)alloc(4194304);    // 8192x128 f32
  float* Vf    = (float*)alloc(4194304);    // 8192x128 f32
  short* WeT   = (short*)alloc(16777216);   // 8x1024x1024 bf16
  float* slot0 = (float*)alloc(33554432);
  float* slot1 = (float*)alloc(33554432);
  int*   bucket  = (int*)alloc(262144);
  float* bucketP = (float*)alloc(262144);
  int*   bucketS = (int*)alloc(262144);
  int*   cnt     = (int*)alloc(256);
  float* entArr  = (float*)alloc(32768);
  int*   e1e2    = (int*)alloc(32768);
  float2* p12    = (float2*)alloc(65536);
  float2* murs   = (float2*)alloc(65536);
  float* attn_out = xln;        // alias: xln dead after QKV GEMM
  short* hln      = (short*)Qs; // alias: Qs dead after attention
  _Float16* WoTh    = (_Float16*)slot0;
  _Float16* WoTl    = (_Float16*)(slot0 + 524288);
  _Float16* BTqkv_h = (_Float16*)slot1;
  _Float16* BTqkv_l = (_Float16*)((char*)slot1 + 2621440);

  hipMemsetAsync(cnt, 0, 256, stream);
  t_w_f16<<<dim3(32, 32), dim3(32, 8), 0, stream>>>(Wq, 1024, BTqkv_h, BTqkv_l, 0);
  t_w_f16<<<dim3(32, 4),  dim3(32, 8), 0, stream>>>(Wk, 128,  BTqkv_h, BTqkv_l, 1024);
  t_w_f16<<<dim3(32, 4),  dim3(32, 8), 0, stream>>>(Wv, 128,  BTqkv_h, BTqkv_l, 1152);
  t_w_f16<<<dim3(32, 32), dim3(32, 8), 0, stream>>>(Wo, 1024, WoTh, WoTl, 0);
  transpose_We<<<dim3(32,32,8), dim3(32,8), 0, stream>>>(We, WeT);

  ln_f32<<<8192, 256, 0, stream>>>(x, ln1g, ln1b, xln);
  gemm_f16x2<0><<<dim3(64,10), 256, 0, stream>>>(xln, BTqkv_h, BTqkv_l, bq, bk, bv,
                                                 nullptr, Qs, Kf, Vf);
  attn_mfma<<<dim3(4,16,32), 256, 0, stream>>>(Qs, Kf, Vf, attn_out);
  gemm_f16x2<1><<<dim3(64,8), 256, 0, stream>>>(attn_out, WoTh, WoTl, bo, nullptr, nullptr,
                                                x, out, nullptr, nullptr);
  ln_bf16<<<8192, 256, 0, stream>>>(out, ln2g, ln2b, hln, murs);
  gating_logits<<<2048, 256, 0, stream>>>(out, murs, ln2g, ln2b, Wg, bg, e1e2, p12, entArr);
  scatter_kernel<<<64, 128, 0, stream>>>(e1e2, p12, cnt, bucket, bucketP, bucketS);
  aux_kernel<<<1, 256, 0, stream>>>(entArr, cnt, out + 8388608);
  moe_gemm<<<dim3(64,8,8), 256, 0, stream>>>(hln, WeT, be, cnt, bucket, bucketP, bucketS, slot0, slot1);
  final_add<<<2048, 256, 0, stream>>>(out, slot0, slot1);
}

// Round 5
// 573.630 us; speedup vs baseline: 2.1778x; 1.0784x over previous
//
#include <hip/hip_runtime.h>
#include <hip/hip_bf16.h>
#include <stdint.h>

// ---------------- types / helpers ----------------
typedef __attribute__((ext_vector_type(8))) short bf16x8;
typedef __attribute__((ext_vector_type(8))) _Float16 f16x8;
typedef __attribute__((ext_vector_type(4))) _Float16 f16x4;
typedef __attribute__((ext_vector_type(4))) float f32x4;

__device__ __forceinline__ short f2bf(float f) {
  __hip_bfloat16 h = __float2bfloat16(f);
  union { __hip_bfloat16 h; short s; } u; u.h = h; return u.s;
}

__device__ __forceinline__ unsigned pk2(float a, float b) {
  union { _Float16 h; unsigned short s; } ua, ub;
  ua.h = (_Float16)a; ub.h = (_Float16)b;
  return (unsigned)ua.s | ((unsigned)ub.s << 16);
}

// async global->LDS, 16B per lane. LDS dest must be wave-uniform base + lane*16.
__device__ __forceinline__ void gld16(const void* g, void* l) {
  __builtin_amdgcn_global_load_lds((const __attribute__((address_space(1))) void*)g,
                                   (__attribute__((address_space(3))) void*)l, 16, 0, 0);
}

__device__ __forceinline__ float wave_sum64(float v) {
  #pragma unroll
  for (int off = 1; off < 64; off <<= 1) v += __shfl_xor(v, off);
  return v;
}
__device__ __forceinline__ double wave_sum64d(double v) {
  #pragma unroll
  for (int off = 1; off < 64; off <<= 1) v += __shfl_xor(v, off);
  return v;
}

// ---------------- LN kernels ----------------
// LN1: emits split-f16 (hi, lo*2048) directly for the DMA GEMM.
__global__ __launch_bounds__(256) void ln_split(const float* __restrict__ x,
    const float* __restrict__ g, const float* __restrict__ b,
    _Float16* __restrict__ xh, _Float16* __restrict__ xl) {
  int t = blockIdx.x, tid = threadIdx.x;
  const float4 v = ((const float4*)(x + (size_t)t * 1024))[tid];
  float s = v.x + v.y + v.z + v.w;
  float s2 = v.x*v.x + v.y*v.y + v.z*v.z + v.w*v.w;
  s = wave_sum64(s); s2 = wave_sum64(s2);
  __shared__ float pa[4], pb[4];
  int wid = tid >> 6, lane = tid & 63;
  if (lane == 0) { pa[wid] = s; pb[wid] = s2; }
  __syncthreads();
  float S = pa[0]+pa[1]+pa[2]+pa[3], S2 = pb[0]+pb[1]+pb[2]+pb[3];
  float mu = S * (1.f/1024.f);
  float var = S2 * (1.f/1024.f) - mu*mu;
  float rs = rsqrtf(var + 1e-5f);
  const float4 gv = ((const float4*)g)[tid];
  const float4 bv = ((const float4*)b)[tid];
  float4 o;
  o.x = (v.x-mu)*rs*gv.x + bv.x; o.y = (v.y-mu)*rs*gv.y + bv.y;
  o.z = (v.z-mu)*rs*gv.z + bv.z; o.w = (v.w-mu)*rs*gv.w + bv.w;
  f16x4 hv, lv;
  hv.x = (_Float16)o.x; lv.x = (_Float16)((o.x - (float)hv.x)*2048.f);
  hv.y = (_Float16)o.y; lv.y = (_Float16)((o.y - (float)hv.y)*2048.f);
  hv.z = (_Float16)o.z; lv.z = (_Float16)((o.z - (float)hv.z)*2048.f);
  hv.w = (_Float16)o.w; lv.w = (_Float16)((o.w - (float)hv.w)*2048.f);
  *(f16x4*)&xh[(size_t)t*1024 + tid*4] = hv;
  *(f16x4*)&xl[(size_t)t*1024 + tid*4] = lv;
}

// LN2: bf16 out + per-token (mu, rs) for gating.
__global__ __launch_bounds__(256) void ln_bf16(const float* __restrict__ x,
    const float* __restrict__ g, const float* __restrict__ b, short* __restrict__ out,
    float2* __restrict__ murs) {
  int t = blockIdx.x, tid = threadIdx.x;
  const float4 v = ((const float4*)(x + (size_t)t * 1024))[tid];
  float s = v.x + v.y + v.z + v.w;
  float s2 = v.x*v.x + v.y*v.y + v.z*v.z + v.w*v.w;
  s = wave_sum64(s); s2 = wave_sum64(s2);
  __shared__ float pa[4], pb[4];
  int wid = tid >> 6, lane = tid & 63;
  if (lane == 0) { pa[wid] = s; pb[wid] = s2; }
  __syncthreads();
  float S = pa[0]+pa[1]+pa[2]+pa[3], S2 = pb[0]+pb[1]+pb[2]+pb[3];
  float mu = S * (1.f/1024.f);
  float var = S2 * (1.f/1024.f) - mu*mu;
  float rs = rsqrtf(var + 1e-5f);
  if (tid == 0) murs[t] = make_float2(mu, rs);
  const float4 gv = ((const float4*)g)[tid];
  const float4 bv = ((const float4*)b)[tid];
  short4 o;
  o.x = f2bf((v.x-mu)*rs*gv.x + bv.x); o.y = f2bf((v.y-mu)*rs*gv.y + bv.y);
  o.z = f2bf((v.z-mu)*rs*gv.z + bv.z); o.w = f2bf((v.w-mu)*rs*gv.w + bv.w);
  ((short4*)(out + (size_t)t * 1024))[tid] = o;
}

// ---------------- weight transpose + fp16 hi/lo split ----------------
__global__ void t_w_f16(const float* __restrict__ src, int srcN,
                        _Float16* __restrict__ dh, _Float16* __restrict__ dl, int dstRow0) {
  __shared__ float tile[32][33];
  int kt = blockIdx.x, nt = blockIdx.y;
  int tx = threadIdx.x, ty = threadIdx.y;
  #pragma unroll
  for (int i = 0; i < 4; i++)
    tile[ty + 8*i][tx] = src[(size_t)(kt*32 + ty + 8*i)*srcN + nt*32 + tx];
  __syncthreads();
  #pragma unroll
  for (int i = 0; i < 4; i++) {
    float v = tile[tx][ty + 8*i];
    _Float16 h = (_Float16)v;
    _Float16 l = (_Float16)((v - (float)h) * 2048.0f);
    size_t o = (size_t)(dstRow0 + nt*32 + ty + 8*i)*1024 + kt*32 + tx;
    dh[o] = h; dl[o] = l;
  }
}

// ---------------- split-fp16 DMA MFMA GEMM ----------------
// A pre-split (Ah, Al*2048) f16 row-major; B pre-transposed/split (BTh, BTl*2048).
// C = accM + accC/2048. LDS staged via global_load_lds w=16, XOR-swizzled 16B chunks.
// MODE 0: fused QKV (y 0..7 -> Q cols; y==8 -> K; y==9 -> V)
// MODE 1: Wo + bias + residual -> fp32 h
template<int MODE>
__global__ __launch_bounds__(256) void gemm_dma(
    const _Float16* __restrict__ Agh, const _Float16* __restrict__ Agl,
    const _Float16* __restrict__ BTh, const _Float16* __restrict__ BTl,
    const float* __restrict__ b0, const float* __restrict__ b1, const float* __restrict__ b2,
    const float* __restrict__ resid,
    float* __restrict__ out0, float* __restrict__ out1, float* __restrict__ out2) {
  int m0 = blockIdx.x * 128;
  int y = blockIdx.y;
  int n0 = y * 128;
  float* dst; const float* biasp; int dcol0, ld;
  if (MODE == 0) {
    if (y < 8)      { dst = out0; biasp = b0 + y*128; dcol0 = y*128; ld = 1024; }
    else if (y == 8){ dst = out1; biasp = b1; dcol0 = 0; ld = 128; }
    else            { dst = out2; biasp = b2; dcol0 = 0; ld = 128; }
  } else            { dst = out0; biasp = b0 + y*128; dcol0 = y*128; ld = 1024; }

  __shared__ _Float16 AhS[8192];   // [128][64] swizzled
  __shared__ _Float16 AlS[8192];
  __shared__ _Float16 BhS[8192];
  __shared__ _Float16 BlS[8192];
  int tid = threadIdx.x;
  int lane = tid & 63, w = tid >> 6;
  int wm = (w & 1) * 64, wn = (w >> 1) * 64;
  int l15 = lane & 15, quad = lane >> 4;

  f32x4 accM[4][4] = {};
  f32x4 accC[4][4] = {};

  for (int kb = 0; kb < 1024; kb += 64) {
    __syncthreads();
    #pragma unroll
    for (int i = 0; i < 4; i++) {
      int P = (i*4 + w)*64 + lane;          // LDS 16B-chunk index (lane-linear)
      int row = P >> 3;
      int c = (P & 7) ^ (row & 7);          // logical col chunk (XOR swizzle)
      size_t goA = (size_t)(m0 + row)*1024 + kb + c*8;
      size_t goB = (size_t)(n0 + row)*1024 + kb + c*8;
      gld16(Agh + goA, &AhS[P*8]);
      gld16(Agl + goA, &AlS[P*8]);
      gld16(BTh + goB, &BhS[P*8]);
      gld16(BTl + goB, &BlS[P*8]);
    }
    __syncthreads();
    #pragma unroll
    for (int ks = 0; ks < 2; ks++) {
      f16x8 bh[4], bl[4];
      #pragma unroll
      for (int nt = 0; nt < 4; nt++) {
        int row = wn + nt*16 + l15;
        int pc = (ks*4 + quad) ^ (row & 7);
        bh[nt] = *(const f16x8*)&BhS[row*64 + pc*8];
        bl[nt] = *(const f16x8*)&BlS[row*64 + pc*8];
      }
      #pragma unroll
      for (int mt = 0; mt < 4; mt++) {
        int row = wm + mt*16 + l15;
        int pc = (ks*4 + quad) ^ (row & 7);
        f16x8 ah = *(const f16x8*)&AhS[row*64 + pc*8];
        f16x8 al = *(const f16x8*)&AlS[row*64 + pc*8];
        #pragma unroll
        for (int nt = 0; nt < 4; nt++) {
          accM[mt][nt] = __builtin_amdgcn_mfma_f32_16x16x32_f16(ah, bh[nt], accM[mt][nt], 0, 0, 0);
          accC[mt][nt] = __builtin_amdgcn_mfma_f32_16x16x32_f16(ah, bl[nt], accC[mt][nt], 0, 0, 0);
          accC[mt][nt] = __builtin_amdgcn_mfma_f32_16x16x32_f16(al, bh[nt], accC[mt][nt], 0, 0, 0);
        }
      }
    }
  }
  const float inv2048 = 1.0f / 2048.0f;
  #pragma unroll
  for (int mt = 0; mt < 4; mt++)
    #pragma unroll
    for (int r = 0; r < 4; r++) {
      int row = m0 + wm + mt*16 + quad*4 + r;
      #pragma unroll
      for (int nt = 0; nt < 4; nt++) {
        int c = wn + nt*16 + l15;
        float v = accM[mt][nt][r] + accC[mt][nt][r]*inv2048 + biasp[c];
        if (MODE == 1) v += resid[(size_t)row*1024 + dcol0 + c];
        dst[(size_t)row*ld + dcol0 + c] = v;
      }
    }
}

// ---------------- MFMA windowed attention ----------------
// Epilogue writes split-f16 (hi, lo*2048) for the Wo DMA GEMM.
__global__ __launch_bounds__(256, 2) void attn_mfma(
    const float* __restrict__ Qs, const float* __restrict__ Kf, const float* __restrict__ Vf,
    _Float16* __restrict__ Oh, _Float16* __restrict__ Ol) {
  int qb = blockIdx.x, n = blockIdx.y;
  int b = blockIdx.z >> 4, h = blockIdx.z & 15;
  int g = h & 1;
  int tid = threadIdx.x;
  int lane = tid & 63, w = tid >> 6;
  int l15 = lane & 15, quad = lane >> 4;

  __shared__ __align__(16) char smem[70912];
  _Float16* Vt = (_Float16*)smem;                 // [64][264]
  _Float16* Qh = (_Float16*)(smem + 33792);       // [64][72]
  _Float16* Ql = (_Float16*)(smem + 43008);
  _Float16* Kh = (_Float16*)(smem + 52224);
  _Float16* Kl = (_Float16*)(smem + 61440);
  _Float16* Pm = (_Float16*)(smem + 33792);       // alias over Q/K
  float*   linv = (float*)(smem + 70656);

  int qtok0 = b*4096 + n*128 + qb*64;
  int key0  = b*4096 + n*128;

  #pragma unroll
  for (int i = 0; i < 4; i++) {
    int idx = tid + 256*i;
    int row = idx >> 4, c4 = idx & 15;
    float4 v = *(const float4*)&Qs[(size_t)(qtok0+row)*1024 + h*64 + c4*4];
    f16x4 hv, lv;
    hv.x = (_Float16)v.x; lv.x = (_Float16)(v.x - (float)hv.x);
    hv.y = (_Float16)v.y; lv.y = (_Float16)(v.y - (float)hv.y);
    hv.z = (_Float16)v.z; lv.z = (_Float16)(v.z - (float)hv.z);
    hv.w = (_Float16)v.w; lv.w = (_Float16)(v.w - (float)hv.w);
    *(f16x4*)&Qh[row*72 + c4*4] = hv;
    *(f16x4*)&Ql[row*72 + c4*4] = lv;
  }
  {
    int kk = tid >> 4, dd = tid & 15;
    #pragma unroll
    for (int i = 0; i < 8; i++) {
      int p = i*16 + kk;
      float4 v0 = *(const float4*)&Vf[(size_t)(key0 + 2*p    )*128 + g*64 + dd*4];
      float4 v1 = *(const float4*)&Vf[(size_t)(key0 + 2*p + 1)*128 + g*64 + dd*4];
      *(unsigned*)&Vt[(dd*4+0)*264 + 2*p] = pk2(v0.x, v1.x);
      *(unsigned*)&Vt[(dd*4+1)*264 + 2*p] = pk2(v0.y, v1.y);
      *(unsigned*)&Vt[(dd*4+2)*264 + 2*p] = pk2(v0.z, v1.z);
      *(unsigned*)&Vt[(dd*4+3)*264 + 2*p] = pk2(v0.w, v1.w);
    }
  }
  __syncthreads();

  f16x8 qh[2], ql[2];
  {
    int qrow = (w*16 + l15)*72;
    qh[0] = *(const f16x8*)&Qh[qrow + quad*8];
    qh[1] = *(const f16x8*)&Qh[qrow + 32 + quad*8];
    ql[0] = *(const f16x8*)&Ql[qrow + quad*8];
    ql[1] = *(const f16x8*)&Ql[qrow + 32 + quad*8];
  }

  f32x4 S[16];
  #pragma unroll
  for (int t = 0; t < 16; t++) S[t] = (f32x4){0.f,0.f,0.f,0.f};

  for (int c = 0; c < 4; c++) {
    if (c) __syncthreads();
    #pragma unroll
    for (int i = 0; i < 4; i++) {
      int idx = tid + 256*i;
      int row = idx >> 4, c4 = idx & 15;
      float4 v = *(const float4*)&Kf[(size_t)(key0 + c*64 + row)*128 + g*64 + c4*4];
      f16x4 hv, lv;
      hv.x = (_Float16)v.x; lv.x = (_Float16)(v.x - (float)hv.x);
      hv.y = (_Float16)v.y; lv.y = (_Float16)(v.y - (float)hv.y);
      hv.z = (_Float16)v.z; lv.z = (_Float16)(v.z - (float)hv.z);
      hv.w = (_Float16)v.w; lv.w = (_Float16)(v.w - (float)hv.w);
      *(f16x4*)&Kh[row*72 + c4*4] = hv;
      *(f16x4*)&Kl[row*72 + c4*4] = lv;
    }
    __syncthreads();
    #pragma unroll
    for (int t = 0; t < 4; t++) {
      int krow = (t*16 + l15)*72;
      f16x8 kh0 = *(const f16x8*)&Kh[krow + quad*8];
      f16x8 kh1 = *(const f16x8*)&Kh[krow + 32 + quad*8];
      f16x8 kl0 = *(const f16x8*)&Kl[krow + quad*8];
      f16x8 kl1 = *(const f16x8*)&Kl[krow + 32 + quad*8];
      int ti = c*4 + t;
      S[ti] = __builtin_amdgcn_mfma_f32_16x16x32_f16(qh[0], kh0, S[ti], 0, 0, 0);
      S[ti] = __builtin_amdgcn_mfma_f32_16x16x32_f16(ql[0], kh0, S[ti], 0, 0, 0);
      S[ti] = __builtin_amdgcn_mfma_f32_16x16x32_f16(qh[0], kl0, S[ti], 0, 0, 0);
      S[ti] = __builtin_amdgcn_mfma_f32_16x16x32_f16(qh[1], kh1, S[ti], 0, 0, 0);
      S[ti] = __builtin_amdgcn_mfma_f32_16x16x32_f16(ql[1], kh1, S[ti], 0, 0, 0);
      S[ti] = __builtin_amdgcn_mfma_f32_16x16x32_f16(qh[1], kl1, S[ti], 0, 0, 0);
    }
  }

  float lrow[4];
  #pragma unroll
  for (int r = 0; r < 4; r++) {
    float mx = S[0][r];
    #pragma unroll
    for (int t = 1; t < 16; t++) mx = fmaxf(mx, S[t][r]);
    mx = fmaxf(mx, __shfl_xor(mx, 1)); mx = fmaxf(mx, __shfl_xor(mx, 2));
    mx = fmaxf(mx, __shfl_xor(mx, 4)); mx = fmaxf(mx, __shfl_xor(mx, 8));
    float sum = 0.f;
    #pragma unroll
    for (int t = 0; t < 16; t++) {
      float e = __expf((S[t][r] - mx) * 0.125f);
      S[t][r] = e; sum += e;
    }
    sum += __shfl_xor(sum, 1); sum += __shfl_xor(sum, 2);
    sum += __shfl_xor(sum, 4); sum += __shfl_xor(sum, 8);
    lrow[r] = sum;
  }
  if (l15 == 0) {
    #pragma unroll
    for (int r = 0; r < 4; r++) linv[w*16 + quad*4 + r] = 1.f / lrow[r];
  }
  __syncthreads();

  #pragma unroll
  for (int r = 0; r < 4; r++) {
    int q = w*16 + quad*4 + r;
    bool mine = (l15 & 1) ? (r >= 2) : (r < 2);
    #pragma unroll
    for (int t = 0; t < 16; t++) {
      float own = S[t][r];
      float oth = __shfl_xor(own, 1);
      if (mine) {
        float e0 = (l15 & 1) ? oth : own;
        float e1 = (l15 & 1) ? own : oth;
        *(unsigned*)&Pm[q*264 + t*16 + (l15 & ~1)] = pk2(e0, e1);
      }
    }
  }
  __syncthreads();

  f32x4 O[4];
  #pragma unroll
  for (int t = 0; t < 4; t++) O[t] = (f32x4){0.f,0.f,0.f,0.f};
  {
    int prow = (w*16 + l15)*264;
    #pragma unroll
    for (int ks = 0; ks < 8; ks++) {
      f16x8 pa = *(const f16x8*)&Pm[prow + ks*32 + quad*8];
      #pragma unroll
      for (int t = 0; t < 4; t++) {
        f16x8 vb = *(const f16x8*)&Vt[(t*16 + l15)*264 + ks*32 + quad*8];
        O[t] = __builtin_amdgcn_mfma_f32_16x16x32_f16(pa, vb, O[t], 0, 0, 0);
      }
    }
  }

  #pragma unroll
  for (int r = 0; r < 4; r++) {
    int qlocal = w*16 + quad*4 + r;
    float inv = linv[qlocal];
    int orow = b*4096 + n*256 + qb*64 + qlocal;
    #pragma unroll
    for (int t = 0; t < 4; t++) {
      float o = O[t][r] * inv;
      _Float16 oh = (_Float16)o;
      _Float16 ol = (_Float16)((o - (float)oh) * 2048.f);
      size_t oo = (size_t)orow*1024 + h*64 + t*16 + l15;
      Oh[oo] = oh; Ol[oo] = ol;
    }
  }
}

// ---------------- gating phase 1: logits + top2 + entropy (NO atomics) ----------------
__global__ __launch_bounds__(256) void gating_logits(
    const float* __restrict__ h, const float2* __restrict__ murs,
    const float* __restrict__ g2, const float* __restrict__ b2,
    const float* __restrict__ Wg, const float* __restrict__ bg,
    int* __restrict__ e1e2, float2* __restrict__ p12, float* __restrict__ entArr) {
  int tid = threadIdx.x, lane = tid & 63, wid = tid >> 6;
  int tok = blockIdx.x*4 + wid;
  const float* row = h + (size_t)tok * 1024;
  float2 mr = murs[tok];
  double mu = (double)mr.x, rs = (double)mr.y;
  double acc[8] = {};
  #pragma unroll
  for (int q = 0; q < 4; q++) {
    float4 xv = ((const float4*)row)[lane*4 + q];
    float4 gv = ((const float4*)g2)[lane*4 + q];
    float4 bv = ((const float4*)b2)[lane*4 + q];
    float xs[4] = {xv.x, xv.y, xv.z, xv.w};
    float gs[4] = {gv.x, gv.y, gv.z, gv.w};
    float bs[4] = {bv.x, bv.y, bv.z, bv.w};
    #pragma unroll
    for (int j = 0; j < 4; j++) {
      int i = lane*16 + q*4 + j;
      double xn = ((double)xs[j] - mu) * rs * (double)gs[j] + (double)bs[j];
      const float4 w0 = *(const float4*)&Wg[(size_t)i*8];
      const float4 w1 = *(const float4*)&Wg[(size_t)i*8 + 4];
      acc[0] += xn*(double)w0.x; acc[1] += xn*(double)w0.y;
      acc[2] += xn*(double)w0.z; acc[3] += xn*(double)w0.w;
      acc[4] += xn*(double)w1.x; acc[5] += xn*(double)w1.y;
      acc[6] += xn*(double)w1.z; acc[7] += xn*(double)w1.w;
    }
  }
  #pragma unroll
  for (int e = 0; e < 8; e++) acc[e] = wave_sum64d(acc[e]) + (double)bg[e];
  int e1 = 0;
  #pragma unroll
  for (int e = 1; e < 8; e++) if (acc[e] > acc[e1]) e1 = e;
  int e2 = (e1 == 0) ? 1 : 0;
  #pragma unroll
  for (int e = 0; e < 8; e++) if (e != e1 && acc[e] > acc[e2]) e2 = e;
  float lf[8];
  #pragma unroll
  for (int e = 0; e < 8; e++) lf[e] = (float)acc[e];
  float mx = lf[0];
  #pragma unroll
  for (int e = 1; e < 8; e++) mx = fmaxf(mx, lf[e]);
  float ex[8], Z = 0.f;
  #pragma unroll
  for (int e = 0; e < 8; e++) { ex[e] = __expf(lf[e] - mx); Z += ex[e]; }
  float invZ = 1.f / Z, ent = 0.f;
  float p[8];
  #pragma unroll
  for (int e = 0; e < 8; e++) { p[e] = ex[e]*invZ; ent -= p[e]*__logf(p[e] + 1e-8f); }
  if (lane == 0) {
    e1e2[tok] = e1 | (e2 << 8);
    p12[tok]  = make_float2(p[e1], p[e2]);
    entArr[tok] = ent;
  }
}

// ---------------- gating phase 2: LDS-aggregated scatter ----------------
__global__ __launch_bounds__(128) void scatter_kernel(
    const int* __restrict__ e1e2, const float2* __restrict__ p12,
    int* __restrict__ cnt, int* __restrict__ bucket, float* __restrict__ bucketP,
    int* __restrict__ bucketS) {
  __shared__ int lcnt[8], base[8];
  int tid = threadIdx.x;
  if (tid < 8) lcnt[tid] = 0;
  __syncthreads();
  int tok = blockIdx.x*128 + tid;
  int ee = e1e2[tok];
  int e1 = ee & 255, e2 = ee >> 8;
  float2 p = p12[tok];
  int o1 = atomicAdd(&lcnt[e1], 1);
  int o2 = atomicAdd(&lcnt[e2], 1);
  __syncthreads();
  if (tid < 8) base[tid] = atomicAdd(&cnt[tid], lcnt[tid]);
  __syncthreads();
  int i1 = base[e1] + o1;
  bucket[e1*8192 + i1] = tok; bucketP[e1*8192 + i1] = p.x; bucketS[e1*8192 + i1] = 0;
  int i2 = base[e2] + o2;
  bucket[e2*8192 + i2] = tok; bucketP[e2*8192 + i2] = p.y; bucketS[e2*8192 + i2] = 1;
}

__global__ __launch_bounds__(256) void aux_kernel(const float* __restrict__ entArr,
    const int* __restrict__ cnt, float* __restrict__ auxOut) {
  int tid = threadIdx.x;
  float s = 0.f;
  for (int i = tid; i < 8192; i += 256) s += entArr[i];
  s = wave_sum64(s);
  __shared__ float pa[4];
  if ((tid & 63) == 0) pa[tid >> 6] = s;
  __syncthreads();
  if (tid == 0) {
    float tot = pa[0]+pa[1]+pa[2]+pa[3];
    float entMean = tot / 8192.f;
    float pen = 0.f;
    for (int e = 0; e < 8; e++) {
      float usage = (float)cnt[e] / (8192.f + 1e-8f);
      pen += fmaxf(usage - 0.4f, 0.f);
    }
    auxOut[0] = 0.05f * entMean + pen;
  }
}

// ---------------- We transpose (fp32 -> bf16, per expert) ----------------
__global__ void transpose_We(const float* __restrict__ We, short* __restrict__ WeT) {
  int e = blockIdx.z;
  __shared__ float tile[32][33];
  int kt = blockIdx.x, nt = blockIdx.y;
  int tx = threadIdx.x, ty = threadIdx.y;
  const float* src = We + (size_t)e * 1048576;
  short* dst = WeT + (size_t)e * 1048576;
  #pragma unroll
  for (int i = 0; i < 4; i++)
    tile[ty + 8*i][tx] = src[(size_t)(kt*32 + ty + 8*i)*1024 + nt*32 + tx];
  __syncthreads();
  #pragma unroll
  for (int i = 0; i < 4; i++)
    dst[(size_t)(nt*32 + ty + 8*i)*1024 + kt*32 + tx] = f2bf(tile[tx][ty + 8*i]);
}

// ---------------- bf16 MFMA grouped MoE GEMM ----------------
__global__ __launch_bounds__(256) void moe_gemm(
    const short* __restrict__ hln, const short* __restrict__ WeT,
    const float* __restrict__ be, const int* __restrict__ cnt,
    const int* __restrict__ bucket, const float* __restrict__ bucketP,
    const int* __restrict__ bucketS,
    float* __restrict__ slot0, float* __restrict__ slot1) {
  int e = blockIdx.z;
  int count = cnt[e];
  int mtile = blockIdx.x;
  if (mtile * 128 >= count) return;
  int n0 = blockIdx.y * 128;
  __shared__ short As[128*72];
  __shared__ short Bs[128*72];
  __shared__ int   toks[128];
  __shared__ float pws[128];
  __shared__ int   sls[128];
  int tid = threadIdx.x;
  if (tid < 128) {
    int idx = mtile*128 + tid;
    int ic = idx < count ? idx : count - 1;
    toks[tid] = bucket[e*8192 + ic];
    pws[tid]  = bucketP[e*8192 + ic];
    sls[tid]  = bucketS[e*8192 + ic];
  }
  __syncthreads();
  int mytok[4];
  #pragma unroll
  for (int i = 0; i < 4; i++) mytok[i] = toks[(tid + 256*i) >> 3];
  const short* Bt = WeT + (size_t)e * 1048576;
  int lane = tid & 63, wid = tid >> 6;
  int wm = (wid & 1) * 64, wn = (wid >> 1) * 64;
  int l15 = lane & 15, quad = lane >> 4;
  f32x4 acc[4][4] = {};
  for (int kb = 0; kb < 1024; kb += 64) {
    __syncthreads();
    #pragma unroll
    for (int i = 0; i < 4; i++) {
      int c = tid + 256*i;
      int row = c >> 3, cb = c & 7;
      *(uint4*)&As[row*72 + cb*8] = *(const uint4*)&hln[(size_t)mytok[i]*1024 + kb + cb*8];
      *(uint4*)&Bs[row*72 + cb*8] = *(const uint4*)&Bt[(size_t)(n0+row)*1024 + kb + cb*8];
    }
    __syncthreads();
    #pragma unroll
    for (int ks = 0; ks < 2; ks++) {
      bf16x8 af[4], bfr[4];
      #pragma unroll
      for (int mt = 0; mt < 4; mt++)
        af[mt] = *(const bf16x8*)&As[(wm + mt*16 + l15)*72 + ks*32 + quad*8];
      #pragma unroll
      for (int nt = 0; nt < 4; nt++)
        bfr[nt] = *(const bf16x8*)&Bs[(wn + nt*16 + l15)*72 + ks*32 + quad*8];
      #pragma unroll
      for (int mt = 0; mt < 4; mt++)
        #pragma unroll
        for (int nt = 0; nt < 4; nt++)
          acc[mt][nt] = __builtin_amdgcn_mfma_f32_16x16x32_bf16(af[mt], bfr[nt], acc[mt][nt], 0, 0, 0);
    }
  }
  #pragma unroll
  for (int mt = 0; mt < 4; mt++) {
    #pragma unroll
    for (int r = 0; r < 4; r++) {
      int m = wm + mt*16 + quad*4 + r;
      if (mtile*128 + m < count) {
        int tok = toks[m];
        float pp = pws[m];
        float* dst = sls[m] ? slot1 : slot0;
        #pragma unroll
        for (int nt = 0; nt < 4; nt++) {
          int col = n0 + wn + nt*16 + l15;
          dst[(size_t)tok*1024 + col] = pp * (acc[mt][nt][r] + be[e*1024 + col]);
        }
      }
    }
  }
}

// ---------------- final combine ----------------
__global__ __launch_bounds__(256) void final_add(float* __restrict__ out,
    const float* __restrict__ s0, const float* __restrict__ s1) {
  const int total = 8388608 / 4;
  for (int i = blockIdx.x*256 + threadIdx.x; i < total; i += gridDim.x*256) {
    float4 a = ((float4*)out)[i];
    const float4 x0 = ((const float4*)s0)[i];
    const float4 x1 = ((const float4*)s1)[i];
    a.x += x0.x + x1.x; a.y += x0.y + x1.y; a.z += x0.z + x1.z; a.w += x0.w + x1.w;
    ((float4*)out)[i] = a;
  }
}

// ---------------- host launcher ----------------
extern "C" void kernel_launch(void* const* d_in, const int* in_sizes, int n_in,
                              void* d_out, int out_size, void* d_ws, size_t ws_size,
                              hipStream_t stream) {
  const float* x    = (const float*)d_in[0];
  const float* Wq   = (const float*)d_in[1];
  const float* bq   = (const float*)d_in[2];
  const float* Wk   = (const float*)d_in[3];
  const float* bk   = (const float*)d_in[4];
  const float* Wv   = (const float*)d_in[5];
  const float* bv   = (const float*)d_in[6];
  const float* Wo   = (const float*)d_in[7];
  const float* bo   = (const float*)d_in[8];
  const float* ln1g = (const float*)d_in[9];
  const float* ln1b = (const float*)d_in[10];
  const float* ln2g = (const float*)d_in[11];
  const float* ln2b = (const float*)d_in[12];
  const float* Wg   = (const float*)d_in[13];
  const float* bg   = (const float*)d_in[14];
  const float* We   = (const float*)d_in[15];
  const float* be   = (const float*)d_in[16];
  float* out = (float*)d_out;

  char* ws = (char*)d_ws;
  size_t off = 0;
  auto alloc = [&](size_t bytes) { char* p = ws + off; off += (bytes + 255) & ~(size_t)255; return p; };
  _Float16* xh  = (_Float16*)alloc(16777216);  // 8192x1024 f16 (LN1 hi); reused as Oh
  _Float16* xl  = (_Float16*)alloc(16777216);  // (LN1 lo*2048); reused as Ol
  float* Qs    = (float*)alloc(33554432);      // 8192x1024 f32; reused as hln
  float* Kf    = (float*)alloc(4194304);
  float* Vf    = (float*)alloc(4194304);
  short* WeT   = (short*)alloc(16777216);
  float* slot0 = (float*)alloc(33554432);
  float* slot1 = (float*)alloc(33554432);
  int*   bucket  = (int*)alloc(262144);
  float* bucketP = (float*)alloc(262144);
  int*   bucketS = (int*)alloc(262144);
  int*   cnt     = (int*)alloc(256);
  float* entArr  = (float*)alloc(32768);
  int*   e1e2    = (int*)alloc(32768);
  float2* p12    = (float2*)alloc(65536);
  float2* murs   = (float2*)alloc(65536);
  _Float16* Oh = xh;            // alias: xh/xl dead after QKV GEMM
  _Float16* Ol = xl;
  short* hln   = (short*)Qs;    // alias: Qs dead after attention
  _Float16* WoTh    = (_Float16*)slot0;
  _Float16* WoTl    = (_Float16*)(slot0 + 524288);
  _Float16* BTqkv_h = (_Float16*)slot1;
  _Float16* BTqkv_l = (_Float16*)((char*)slot1 + 2621440);

  hipMemsetAsync(cnt, 0, 256, stream);
  t_w_f16<<<dim3(32, 32), dim3(32, 8), 0, stream>>>(Wq, 1024, BTqkv_h, BTqkv_l, 0);
  t_w_f16<<<dim3(32, 4),  dim3(32, 8), 0, stream>>>(Wk, 128,  BTqkv_h, BTqkv_l, 1024);
  t_w_f16<<<dim3(32, 4),  dim3(32, 8), 0, stream>>>(Wv, 128,  BTqkv_h, BTqkv_l, 1152);
  t_w_f16<<<dim3(32, 32), dim3(32, 8), 0, stream>>>(Wo, 1024, WoTh, WoTl, 0);
  transpose_We<<<dim3(32,32,8), dim3(32,8), 0, stream>>>(We, WeT);

  ln_split<<<8192, 256, 0, stream>>>(x, ln1g, ln1b, xh, xl);
  gemm_dma<0><<<dim3(64,10), 256, 0, stream>>>(xh, xl, BTqkv_h, BTqkv_l, bq, bk, bv,
                                               nullptr, Qs, Kf, Vf);
  attn_mfma<<<dim3(4,16,32), 256, 0, stream>>>(Qs, Kf, Vf, Oh, Ol);
  gemm_dma<1><<<dim3(64,8), 256, 0, stream>>>(Oh, Ol, WoTh, WoTl, bo, nullptr, nullptr,
                                              x, out, nullptr, nullptr);
  ln_bf16<<<8192, 256, 0, stream>>>(out, ln2g, ln2b, hln, murs);
  gating_logits<<<2048, 256, 0, stream>>>(out, murs, ln2g, ln2b, Wg, bg, e1e2, p12, entArr);
  scatter_kernel<<<64, 128, 0, stream>>>(e1e2, p12, cnt, bucket, bucketP, bucketS);
  aux_kernel<<<1, 256, 0, stream>>>(entArr, cnt, out + 8388608);
  moe_gemm<<<dim3(64,8,8), 256, 0, stream>>>(hln, WeT, be, cnt, bucket, bucketP, bucketS, slot0, slot1);
  final_add<<<2048, 256, 0, stream>>>(out, slot0, slot1);
}